// Round 3
// baseline (367.965 us; speedup 1.0000x reference)
//
#include <hip/hip_runtime.h>

#define N_NODES 50000
#define N_EDGES 800000
#define FEATS   128
#define HID     32
#define HEADS   4
#define D1      128      // HEADS*HID
#define NGRAPH  64

__device__ __forceinline__ float lrelu_(float v) { return v > 0.f ? v : 0.2f * v; }
__device__ __forceinline__ float elu_(float v)   { return v > 0.f ? v : __expf(v) - 1.f; }

// ---------- fused prep: wtrans1 | wtrans2 | zero(deg,cur) | gbound ----------
// block ranges: [0,128) wtrans1, [128,160) wtrans2, [160,551) zero, [551,747) gbound
__global__ __launch_bounds__(256) void k_prep(
    const float* __restrict__ w1l, const float* __restrict__ w1r, float* __restrict__ wtg1,
    const float* __restrict__ w2l, const float* __restrict__ w2r, float* __restrict__ wtg2,
    int* __restrict__ deg, int* __restrict__ cur,
    const int* __restrict__ batch, int* __restrict__ gstart)
{
    int b = blockIdx.x;
    if (b < 128) {
        int idx = b * 256 + threadIdx.x;            // 32768 = 32*256*4
        int kk = idx & 3, j = (idx >> 2) & 255, k4 = idx >> 10;
        int k = k4 * 4 + kk;
        wtg1[idx] = (j < 128) ? w1l[j * FEATS + k] : w1r[(j - 128) * FEATS + k];
    } else if (b < 160) {
        int idx = (b - 128) * 256 + threadIdx.x;    // 8192 = 32*64*4
        int kk = idx & 3, j = (idx >> 2) & 63, k4 = idx >> 8;
        int k = k4 * 4 + kk;
        wtg2[idx] = (j < 32) ? w2l[j * D1 + k] : w2r[(j - 32) * D1 + k];
    } else if (b < 551) {
        int i = (b - 160) * 256 + threadIdx.x;      // 100000
        if (i < N_NODES) deg[i] = 0;
        else if (i < 2 * N_NODES) cur[i - N_NODES] = 0;
    } else {
        int i = (b - 551) * 256 + threadIdx.x;      // 50001
        if (i > N_NODES) return;
        int bb   = (i < N_NODES) ? batch[i] : NGRAPH;
        int prev = (i == 0) ? -1 : batch[i - 1];
        for (int g = prev + 1; g <= bb; ++g) gstart[g] = i;
    }
}

// ---------- CSR build ----------
__global__ __launch_bounds__(256) void k_hist(const int* __restrict__ ei, int* __restrict__ deg)
{
    int e = blockIdx.x * 256 + threadIdx.x;
    if (e < N_EDGES) atomicAdd(&deg[ei[N_EDGES + e]], 1);
}

// single-block scan of 50001 row offsets: 49 elems/thread in registers + block scan
__global__ __launch_bounds__(1024) void k_scan_all(
    const int* __restrict__ deg, int* __restrict__ rs)
{
    __shared__ int sm[1024];
    const int PER = 49;                       // 1024*49 = 50176 >= 50000
    int t = threadIdx.x;
    int base = t * PER;
    int v[PER];
    int sum = 0;
#pragma unroll
    for (int i = 0; i < PER; ++i) {
        int idx = base + i;
        int d = (idx < N_NODES) ? deg[idx] : 0;
        v[i] = sum;                            // local exclusive prefix
        sum += d;
    }
    sm[t] = sum;
    __syncthreads();
    for (int off = 1; off < 1024; off <<= 1) {
        int u = (t >= off) ? sm[t - off] : 0;
        __syncthreads();
        sm[t] += u;
        __syncthreads();
    }
    int boff = sm[t] - sum;                    // exclusive offset of this thread's chunk
#pragma unroll
    for (int i = 0; i < PER; ++i) {
        int idx = base + i;
        if (idx < N_NODES) rs[idx] = boff + v[i];
    }
    if (t == 0) rs[N_NODES] = N_EDGES;
}

__global__ __launch_bounds__(256) void k_scatter(const int* __restrict__ ei,
                                                const int* __restrict__ rs,
                                                int* __restrict__ cur,
                                                int* __restrict__ csr_src)
{
    int e = blockIdx.x * 256 + threadIdx.x;
    if (e >= N_EDGES) return;
    int d = ei[N_EDGES + e];
    int p = rs[d] + atomicAdd(&cur[d], 1);
    csr_src[p] = ei[e];
}

// ---------- conv1 transform: 32 nodes/block, 8 nodes/thread ----------
// 3-buffer hand-pipelined weight prefetch, distance 2 (>=500cy cover), no launch-bounds cap.
#define LOADW1(BUF, KP) { int kp_ = (KP); if (kp_ > 31) kp_ = 31; \
    _Pragma("unroll") for (int c = 0; c < 4; ++c) BUF[c] = wp[kp_ * 256 + jg + 64 * c]; }

#define COMP1(KK, W) { \
    float4 xv[8]; \
    _Pragma("unroll") for (int r = 0; r < 8; ++r) xv[r] = xs[r0 + r][KK]; \
    _Pragma("unroll") for (int c = 0; c < 4; ++c) \
    _Pragma("unroll") for (int r = 0; r < 8; ++r) \
        acc[r][c] = fmaf(W[c].x, xv[r].x, fmaf(W[c].y, xv[r].y, \
                    fmaf(W[c].z, xv[r].z, fmaf(W[c].w, xv[r].w, acc[r][c])))); }

__global__ __launch_bounds__(256) void k_transform1(
    const float* __restrict__ x, const float* __restrict__ wtg,
    const float* __restrict__ bl, const float* __restrict__ br,
    float* __restrict__ xl, float* __restrict__ xr)
{
    __shared__ float4 xs[32][32];   // [node][k4] : 16 KB
    int node0 = blockIdx.x * 32;
    for (int i = threadIdx.x; i < 1024; i += 256) {
        int r = i >> 5, k4 = i & 31;
        int n = node0 + r; if (n > N_NODES - 1) n = N_NODES - 1;   // tail clamp (benign dup)
        xs[r][k4] = *(const float4*)&x[(size_t)n * FEATS + k4 * 4];
    }
    __syncthreads();
    int jg = threadIdx.x & 63;
    int r0 = (threadIdx.x >> 6) * 8;
    const float4* __restrict__ wp = (const float4*)wtg;
    float acc[8][4];
#pragma unroll
    for (int r = 0; r < 8; ++r)
#pragma unroll
        for (int c = 0; c < 4; ++c) acc[r][c] = 0.f;

    float4 wb0[4], wb1[4], wb2[4];
    LOADW1(wb0, 0) LOADW1(wb1, 1) LOADW1(wb2, 2)

    for (int k = 0; k < 28; k += 3) {          // bodies k=0..27 -> computes 0..29
        COMP1(k,     wb0) LOADW1(wb0, k + 3)
        COMP1(k + 1, wb1) LOADW1(wb1, k + 4)
        COMP1(k + 2, wb2) LOADW1(wb2, k + 5)
    }
    COMP1(30, wb0)
    COMP1(31, wb1)

    float bl0 = bl[jg], bl1 = bl[jg + 64];
    float br0 = br[jg], br1 = br[jg + 64];
#pragma unroll
    for (int r = 0; r < 8; ++r) {
        int nn = node0 + r0 + r; if (nn > N_NODES - 1) nn = N_NODES - 1;
        size_t n = (size_t)nn;
        xl[n * D1 + jg]      = acc[r][0] + bl0;
        xl[n * D1 + jg + 64] = acc[r][1] + bl1;
        xr[n * D1 + jg]      = acc[r][2] + br0;
        xr[n * D1 + jg + 64] = acc[r][3] + br1;
    }
}

// ---------- conv2 transform: 64 nodes/block, 8 nodes/thread, 2 cols/thread ----------
#define LOADW2(BUF, KP) { int kp_ = (KP); if (kp_ > 31) kp_ = 31; \
    BUF[0] = wp[kp_ * 64 + j]; BUF[1] = wp[kp_ * 64 + j + 32]; }

#define COMP2(KK, W) { \
    float4 xv[8]; \
    _Pragma("unroll") for (int r = 0; r < 8; ++r) xv[r] = xs[r0 + r][KK]; \
    _Pragma("unroll") for (int r = 0; r < 8; ++r) { \
        accl[r] = fmaf(W[0].x, xv[r].x, fmaf(W[0].y, xv[r].y, \
                  fmaf(W[0].z, xv[r].z, fmaf(W[0].w, xv[r].w, accl[r])))); \
        accr[r] = fmaf(W[1].x, xv[r].x, fmaf(W[1].y, xv[r].y, \
                  fmaf(W[1].z, xv[r].z, fmaf(W[1].w, xv[r].w, accr[r])))); } }

__global__ __launch_bounds__(256) void k_transform2(
    const float* __restrict__ hin, const float* __restrict__ wtg,
    const float* __restrict__ bl, const float* __restrict__ br,
    float* __restrict__ xl2, float* __restrict__ xr2)
{
    __shared__ float4 xs[64][32];   // 32 KB
    int node0 = blockIdx.x * 64;
    for (int i = threadIdx.x; i < 2048; i += 256) {
        int r = i >> 5, k4 = i & 31;
        int n = node0 + r; if (n > N_NODES - 1) n = N_NODES - 1;
        xs[r][k4] = *(const float4*)&hin[(size_t)n * D1 + k4 * 4];
    }
    __syncthreads();
    int j  = threadIdx.x & 31;        // output col (L and R side)
    int r0 = (threadIdx.x >> 5) * 8;  // 8 groups x 8 nodes = 64
    const float4* __restrict__ wp = (const float4*)wtg;
    float accl[8], accr[8];
#pragma unroll
    for (int r = 0; r < 8; ++r) { accl[r] = 0.f; accr[r] = 0.f; }

    float4 wb0[2], wb1[2], wb2[2];
    LOADW2(wb0, 0) LOADW2(wb1, 1) LOADW2(wb2, 2)

    for (int k = 0; k < 28; k += 3) {
        COMP2(k,     wb0) LOADW2(wb0, k + 3)
        COMP2(k + 1, wb1) LOADW2(wb1, k + 4)
        COMP2(k + 2, wb2) LOADW2(wb2, k + 5)
    }
    COMP2(30, wb0)
    COMP2(31, wb1)

    float bls = bl[j], brs = br[j];
#pragma unroll
    for (int r = 0; r < 8; ++r) {
        int nn = node0 + r0 + r; if (nn > N_NODES - 1) nn = N_NODES - 1;
        size_t n = (size_t)nn;
        xl2[n * HID + j] = accl[r] + bls;
        xr2[n * HID + j] = accr[r] + brs;
    }
}

// ---------- conv1 fused: wave per node, 2 edges/wave, float4 (16B) gathers ----------
__global__ __launch_bounds__(256) void k_gat1_fused(
    const int* __restrict__ rs, const int* __restrict__ csr_src,
    const float* __restrict__ xl, const float* __restrict__ xr,
    const float* __restrict__ att, const float* __restrict__ bias,
    float* __restrict__ hout)
{
    int n = (blockIdx.x * 256 + threadIdx.x) >> 6;
    if (n >= N_NODES) return;
    int lane = threadIdx.x & 63;
    int d0   = lane & 31;
    int half = lane >> 5;
    const float4* xlp = (const float4*)xl;
    float4 r = ((const float4*)xr)[(size_t)n * 32 + d0];
    float4 a = ((const float4*)att)[d0];   // att[h*32 + c] -> float4 index == d0
    float4 l = xlp[(size_t)n * 32 + d0];
    float sc = lrelu_(l.x + r.x) * a.x + lrelu_(l.y + r.y) * a.y
             + lrelu_(l.z + r.z) * a.z + lrelu_(l.w + r.w) * a.w;
    sc += __shfl_xor(sc, 1);
    sc += __shfl_xor(sc, 2);
    sc += __shfl_xor(sc, 4);
    float ex  = (half == 0) ? __expf(sc) : 0.f;
    float den = ex;
    float4 acc = { ex * l.x, ex * l.y, ex * l.z, ex * l.w };
    int e0 = rs[n], e1 = rs[n + 1];
    int p = e0;
    for (; p + 8 <= e1; p += 8) {        // 4 pairs = 8 edges, all valid
        int    sA[4];
        float4 ll[4];
        float  sb[4];
#pragma unroll
        for (int i = 0; i < 4; ++i) sA[i] = csr_src[p + 2 * i + half];
#pragma unroll
        for (int i = 0; i < 4; ++i) ll[i] = xlp[(size_t)sA[i] * 32 + d0];
#pragma unroll
        for (int i = 0; i < 4; ++i)
            sb[i] = lrelu_(ll[i].x + r.x) * a.x + lrelu_(ll[i].y + r.y) * a.y
                  + lrelu_(ll[i].z + r.z) * a.z + lrelu_(ll[i].w + r.w) * a.w;
#pragma unroll
        for (int i = 0; i < 4; ++i) sb[i] += __shfl_xor(sb[i], 1);
#pragma unroll
        for (int i = 0; i < 4; ++i) sb[i] += __shfl_xor(sb[i], 2);
#pragma unroll
        for (int i = 0; i < 4; ++i) sb[i] += __shfl_xor(sb[i], 4);
#pragma unroll
        for (int i = 0; i < 4; ++i) {
            float exx = __expf(sb[i]);
            den   += exx;
            acc.x += exx * ll[i].x;
            acc.y += exx * ll[i].y;
            acc.z += exx * ll[i].z;
            acc.w += exx * ll[i].w;
        }
    }
    for (; p < e1; p += 2) {             // tail pairs, half-validity masked
        int  idx = p + half;
        bool v   = idx < e1;
        int  s   = csr_src[v ? idx : e1 - 1];
        float4 ll = xlp[(size_t)s * 32 + d0];
        float  s1 = lrelu_(ll.x + r.x) * a.x + lrelu_(ll.y + r.y) * a.y
                  + lrelu_(ll.z + r.z) * a.z + lrelu_(ll.w + r.w) * a.w;
        s1 += __shfl_xor(s1, 1);
        s1 += __shfl_xor(s1, 2);
        s1 += __shfl_xor(s1, 4);
        float exx = v ? __expf(s1) : 0.f;
        den   += exx;
        acc.x += exx * ll.x;
        acc.y += exx * ll.y;
        acc.z += exx * ll.z;
        acc.w += exx * ll.w;
    }
    den   += __shfl_xor(den, 32);
    acc.x += __shfl_xor(acc.x, 32);
    acc.y += __shfl_xor(acc.y, 32);
    acc.z += __shfl_xor(acc.z, 32);
    acc.w += __shfl_xor(acc.w, 32);
    if (half == 0) {
        float inv = 1.f / (den + 1e-16f);
        float4 b = ((const float4*)bias)[d0];
        float4 o;
        o.x = elu_(acc.x * inv + b.x);
        o.y = elu_(acc.y * inv + b.y);
        o.z = elu_(acc.z * inv + b.z);
        o.w = elu_(acc.w * inv + b.w);
        ((float4*)hout)[(size_t)n * 32 + d0] = o;   // hout aliases xr: own row only
    }
}

// ---------- conv2 fused: half-wave per node, 4 edges in flight, float4 gathers ----------
__global__ __launch_bounds__(256) void k_gat2_fused(
    const int* __restrict__ rs, const int* __restrict__ csr_src,
    const float* __restrict__ xl2, const float* __restrict__ xr2,
    const float* __restrict__ att, const float* __restrict__ bias,
    float* __restrict__ h2)
{
    int n = (blockIdx.x * 256 + threadIdx.x) >> 5;
    if (n >= N_NODES) return;
    int lane = threadIdx.x & 31;
    int d0   = lane & 7;
    int sub  = lane >> 3;
    const float4* xlp = (const float4*)xl2;
    float4 r = ((const float4*)xr2)[(size_t)n * 8 + d0];
    float4 a = ((const float4*)att)[d0];
    float4 l = xlp[(size_t)n * 8 + d0];
    float sc = lrelu_(l.x + r.x) * a.x + lrelu_(l.y + r.y) * a.y
             + lrelu_(l.z + r.z) * a.z + lrelu_(l.w + r.w) * a.w;
    sc += __shfl_xor(sc, 1);
    sc += __shfl_xor(sc, 2);
    sc += __shfl_xor(sc, 4);
    float ex  = (sub == 0) ? __expf(sc) : 0.f;
    float den = ex;
    float4 acc = { ex * l.x, ex * l.y, ex * l.z, ex * l.w };
    int e0 = rs[n], e1 = rs[n + 1];
    int p = e0;
    for (; p + 16 <= e1; p += 16) {      // 4 quads = 16 edges
        int    sA[4];
        float4 ll[4];
        float  sb[4];
#pragma unroll
        for (int i = 0; i < 4; ++i) sA[i] = csr_src[p + 4 * i + sub];
#pragma unroll
        for (int i = 0; i < 4; ++i) ll[i] = xlp[(size_t)sA[i] * 8 + d0];
#pragma unroll
        for (int i = 0; i < 4; ++i)
            sb[i] = lrelu_(ll[i].x + r.x) * a.x + lrelu_(ll[i].y + r.y) * a.y
                  + lrelu_(ll[i].z + r.z) * a.z + lrelu_(ll[i].w + r.w) * a.w;
#pragma unroll
        for (int i = 0; i < 4; ++i) sb[i] += __shfl_xor(sb[i], 1);
#pragma unroll
        for (int i = 0; i < 4; ++i) sb[i] += __shfl_xor(sb[i], 2);
#pragma unroll
        for (int i = 0; i < 4; ++i) sb[i] += __shfl_xor(sb[i], 4);
#pragma unroll
        for (int i = 0; i < 4; ++i) {
            float exx = __expf(sb[i]);
            den   += exx;
            acc.x += exx * ll[i].x;
            acc.y += exx * ll[i].y;
            acc.z += exx * ll[i].z;
            acc.w += exx * ll[i].w;
        }
    }
    for (; p < e1; p += 4) {             // tail quads, validity masked
        int  idx = p + sub;
        bool v   = idx < e1;
        int  s   = csr_src[v ? idx : e1 - 1];
        float4 ll = xlp[(size_t)s * 8 + d0];
        float  s1 = lrelu_(ll.x + r.x) * a.x + lrelu_(ll.y + r.y) * a.y
                  + lrelu_(ll.z + r.z) * a.z + lrelu_(ll.w + r.w) * a.w;
        s1 += __shfl_xor(s1, 1);
        s1 += __shfl_xor(s1, 2);
        s1 += __shfl_xor(s1, 4);
        float exx = v ? __expf(s1) : 0.f;
        den   += exx;
        acc.x += exx * ll.x;
        acc.y += exx * ll.y;
        acc.z += exx * ll.z;
        acc.w += exx * ll.w;
    }
    den   += __shfl_xor(den, 8);
    den   += __shfl_xor(den, 16);
    acc.x += __shfl_xor(acc.x, 8);  acc.x += __shfl_xor(acc.x, 16);
    acc.y += __shfl_xor(acc.y, 8);  acc.y += __shfl_xor(acc.y, 16);
    acc.z += __shfl_xor(acc.z, 8);  acc.z += __shfl_xor(acc.z, 16);
    acc.w += __shfl_xor(acc.w, 8);  acc.w += __shfl_xor(acc.w, 16);
    if (sub == 0) {
        float inv = 1.f / (den + 1e-16f);
        float4 b = ((const float4*)bias)[d0];
        float4 o;
        o.x = elu_(acc.x * inv + b.x);
        o.y = elu_(acc.y * inv + b.y);
        o.z = elu_(acc.z * inv + b.z);
        o.w = elu_(acc.w * inv + b.w);
        ((float4*)h2)[(size_t)n * 8 + d0] = o;
    }
}

// ---------- per-graph mean pool + both heads ----------
__global__ __launch_bounds__(256) void k_pool_heads(
    const float* __restrict__ h2, const int* __restrict__ gstart,
    const float* __restrict__ wc, const float* __restrict__ bc,
    const float* __restrict__ wp, const float* __restrict__ bp,
    float* __restrict__ out)
{
    int g  = blockIdx.x;
    int n0 = gstart[g], n1 = gstart[g + 1];
    int c    = threadIdx.x & 31;
    int slot = threadIdx.x >> 5;   // 0..7
    float s = 0.f;
    for (int n = n0 + slot; n < n1; n += 8)
        s += h2[n * HID + c];
    __shared__ float red[8][HID];
    red[slot][c] = s;
    __syncthreads();
    if (slot == 0) {
        float tot = 0.f;
#pragma unroll
        for (int i = 0; i < 8; ++i) tot += red[i][c];
        float cntf = fmaxf((float)(n1 - n0), 1.f);
        float p = tot / cntf;
        float sc = p * wc[c];
        float sp = p * wp[c];
        sc += __shfl_xor(sc, 1);  sp += __shfl_xor(sp, 1);
        sc += __shfl_xor(sc, 2);  sp += __shfl_xor(sp, 2);
        sc += __shfl_xor(sc, 4);  sp += __shfl_xor(sp, 4);
        sc += __shfl_xor(sc, 8);  sp += __shfl_xor(sp, 8);
        sc += __shfl_xor(sc, 16); sp += __shfl_xor(sp, 16);
        if (c == 0) {
            out[g]          = sc + bc[0];
            out[NGRAPH + g] = sp + bp[0];
        }
    }
}

extern "C" void kernel_launch(void* const* d_in, const int* in_sizes, int n_in,
                              void* d_out, int out_size, void* d_ws, size_t ws_size,
                              hipStream_t stream)
{
    const float* x     = (const float*)d_in[0];
    const int*   ei    = (const int*)d_in[1];
    const int*   batch = (const int*)d_in[2];
    const float* w1l   = (const float*)d_in[3];
    const float* b1l   = (const float*)d_in[4];
    const float* w1r   = (const float*)d_in[5];
    const float* b1r   = (const float*)d_in[6];
    const float* att1  = (const float*)d_in[7];
    const float* bias1 = (const float*)d_in[8];
    const float* w2l   = (const float*)d_in[9];
    const float* b2l   = (const float*)d_in[10];
    const float* w2r   = (const float*)d_in[11];
    const float* b2r   = (const float*)d_in[12];
    const float* att2  = (const float*)d_in[13];
    const float* bias2 = (const float*)d_in[14];
    const float* wc    = (const float*)d_in[15];
    const float* bc    = (const float*)d_in[16];
    const float* wp    = (const float*)d_in[17];
    const float* bp    = (const float*)d_in[18];
    float* out = (float*)d_out;

    float* ws   = (float*)d_ws;
    // conv1 phase
    float* xl1  = ws;                 // 6,400,000 floats   [0 .. 6.4M)
    float* xr1  = ws + 6400000;       // 6,400,000          [6.4M .. 12.8M)
    float* hbuf = ws + 6400000;       // ALIASES xr1 (safe: per-wave read-own-row-then-write)
    // conv2 phase (xl1 region dead after k_gat1_fused)
    float* xl2  = ws;                 // 1,600,000
    float* xr2  = ws + 1600000;       // 1,600,000
    float* h2   = ws + 3200000;       // 1,600,000
    // int region (after 12.8M floats)
    int* ibase   = (int*)(ws + 12800000);
    int* deg     = ibase;              //  50,000
    int* rs      = ibase + 50000;      //  50,001
    int* cur     = ibase + 100001;     //  50,000
    int* csr_src = ibase + 150001;     // 800,000
    int* gstart  = ibase + 950001;     //      65
    // re-laid-out weights
    float* wtg1 = ws + 13800000;       // 32,768
    float* wtg2 = ws + 13840000;       //  8,192

    // ---- fused prep (wtrans1+wtrans2+zero+gbound), then CSR build ----
    k_prep<<<747, 256, 0, stream>>>(w1l, w1r, wtg1, w2l, w2r, wtg2, deg, cur, batch, gstart);
    k_hist<<<(N_EDGES + 255) / 256, 256, 0, stream>>>(ei, deg);
    k_scan_all<<<1, 1024, 0, stream>>>(deg, rs);
    k_scatter<<<(N_EDGES + 255) / 256, 256, 0, stream>>>(ei, rs, cur, csr_src);

    // ---- conv1 ----
    k_transform1<<<(N_NODES + 31) / 32, 256, 0, stream>>>(x, wtg1, b1l, b1r, xl1, xr1);
    k_gat1_fused<<<(N_NODES * 64 + 255) / 256, 256, 0, stream>>>(rs, csr_src, xl1, xr1, att1, bias1, hbuf);

    // ---- conv2 ----
    k_transform2<<<(N_NODES + 63) / 64, 256, 0, stream>>>(hbuf, wtg2, b2l, b2r, xl2, xr2);
    k_gat2_fused<<<(N_NODES * 32 + 255) / 256, 256, 0, stream>>>(rs, csr_src, xl2, xr2, att2, bias2, h2);

    // ---- pool + heads ----
    k_pool_heads<<<NGRAPH, 256, 0, stream>>>(h2, gstart, wc, bc, wp, bp, out);
}

// Round 4
// 331.232 us; speedup vs baseline: 1.1109x; 1.1109x over previous
//
#include <hip/hip_runtime.h>

#define N_NODES 50000
#define N_EDGES 800000
#define FEATS   128
#define HID     32
#define HEADS   4
#define D1      128      // HEADS*HID
#define NGRAPH  64

__device__ __forceinline__ float lrelu_(float v) { return v > 0.f ? v : 0.2f * v; }
__device__ __forceinline__ float elu_(float v)   { return v > 0.f ? v : __expf(v) - 1.f; }

// ---------- fused prep: wtrans1 | wtrans2 | zero(deg,cur) | gbound ----------
// block ranges: [0,128) wtrans1, [128,160) wtrans2, [160,551) zero, [551,747) gbound
__global__ __launch_bounds__(256) void k_prep(
    const float* __restrict__ w1l, const float* __restrict__ w1r, float* __restrict__ wtg1,
    const float* __restrict__ w2l, const float* __restrict__ w2r, float* __restrict__ wtg2,
    int* __restrict__ deg, int* __restrict__ cur,
    const int* __restrict__ batch, int* __restrict__ gstart)
{
    int b = blockIdx.x;
    if (b < 128) {
        int idx = b * 256 + threadIdx.x;            // 32768 = 32*256*4
        int kk = idx & 3, j = (idx >> 2) & 255, k4 = idx >> 10;
        int k = k4 * 4 + kk;
        wtg1[idx] = (j < 128) ? w1l[j * FEATS + k] : w1r[(j - 128) * FEATS + k];
    } else if (b < 160) {
        int idx = (b - 128) * 256 + threadIdx.x;    // 8192 = 32*64*4
        int kk = idx & 3, j = (idx >> 2) & 63, k4 = idx >> 8;
        int k = k4 * 4 + kk;
        wtg2[idx] = (j < 32) ? w2l[j * D1 + k] : w2r[(j - 32) * D1 + k];
    } else if (b < 551) {
        int i = (b - 160) * 256 + threadIdx.x;      // 100000
        if (i < N_NODES) deg[i] = 0;
        else if (i < 2 * N_NODES) cur[i - N_NODES] = 0;
    } else {
        int i = (b - 551) * 256 + threadIdx.x;      // 50001
        if (i > N_NODES) return;
        int bb   = (i < N_NODES) ? batch[i] : NGRAPH;
        int prev = (i == 0) ? -1 : batch[i - 1];
        for (int g = prev + 1; g <= bb; ++g) gstart[g] = i;
    }
}

// ---------- CSR build ----------
__global__ __launch_bounds__(256) void k_hist(const int* __restrict__ ei, int* __restrict__ deg)
{
    int e = blockIdx.x * 256 + threadIdx.x;
    if (e < N_EDGES) atomicAdd(&deg[ei[N_EDGES + e]], 1);
}

// single-block scan of 50001 row offsets: 49 elems/thread in registers + block scan
__global__ __launch_bounds__(1024) void k_scan_all(
    const int* __restrict__ deg, int* __restrict__ rs)
{
    __shared__ int sm[1024];
    const int PER = 49;                       // 1024*49 = 50176 >= 50000
    int t = threadIdx.x;
    int base = t * PER;
    int v[PER];
    int sum = 0;
#pragma unroll
    for (int i = 0; i < PER; ++i) {
        int idx = base + i;
        int d = (idx < N_NODES) ? deg[idx] : 0;
        v[i] = sum;                            // local exclusive prefix
        sum += d;
    }
    sm[t] = sum;
    __syncthreads();
    for (int off = 1; off < 1024; off <<= 1) {
        int u = (t >= off) ? sm[t - off] : 0;
        __syncthreads();
        sm[t] += u;
        __syncthreads();
    }
    int boff = sm[t] - sum;                    // exclusive offset of this thread's chunk
#pragma unroll
    for (int i = 0; i < PER; ++i) {
        int idx = base + i;
        if (idx < N_NODES) rs[idx] = boff + v[i];
    }
    if (t == 0) rs[N_NODES] = N_EDGES;
}

__global__ __launch_bounds__(256) void k_scatter(const int* __restrict__ ei,
                                                const int* __restrict__ rs,
                                                int* __restrict__ cur,
                                                int* __restrict__ csr_src)
{
    int e = blockIdx.x * 256 + threadIdx.x;
    if (e >= N_EDGES) return;
    int d = ei[N_EDGES + e];
    int p = rs[d] + atomicAdd(&cur[d], 1);
    csr_src[p] = ei[e];
}

// ---------- conv1 transform: 64 nodes/block, 16 nodes/thread ----------
// round-2 structure (compiler-scheduled w/wn distance-1 prefetch), tile doubled:
// per k4 a wave now runs 256 FMAs against 4 weight loads -> 512cy cover, and
// total weight L2 traffic halves (3126 waves x 128KB).
__global__ __launch_bounds__(256) void k_transform1(
    const float* __restrict__ x, const float* __restrict__ wtg,
    const float* __restrict__ bl, const float* __restrict__ br,
    float* __restrict__ xl, float* __restrict__ xr)
{
    __shared__ float4 xs[64][32];   // [node][k4] : 32 KB
    int node0 = blockIdx.x * 64;
    for (int i = threadIdx.x; i < 2048; i += 256) {
        int r = i >> 5, k4 = i & 31;
        int n = node0 + r; if (n > N_NODES - 1) n = N_NODES - 1;   // tail clamp (benign dup)
        xs[r][k4] = *(const float4*)&x[(size_t)n * FEATS + k4 * 4];
    }
    __syncthreads();
    int jg = threadIdx.x & 63;
    int r0 = (threadIdx.x >> 6) * 16;
    const float4* __restrict__ wp = (const float4*)wtg;
    float acc[16][4];
#pragma unroll
    for (int r = 0; r < 16; ++r)
#pragma unroll
        for (int c = 0; c < 4; ++c) acc[r][c] = 0.f;

    float4 w[4];
#pragma unroll
    for (int c = 0; c < 4; ++c) w[c] = wp[jg + 64 * c];

    for (int k4 = 0; k4 < 32; ++k4) {
        int k4n = (k4 < 31) ? k4 + 1 : 31;
        float4 wn[4];
#pragma unroll
        for (int c = 0; c < 4; ++c) wn[c] = wp[k4n * 256 + jg + 64 * c];
#pragma unroll
        for (int h = 0; h < 2; ++h) {
            float4 xv[8];
#pragma unroll
            for (int r = 0; r < 8; ++r) xv[r] = xs[r0 + h * 8 + r][k4];
#pragma unroll
            for (int c = 0; c < 4; ++c)
#pragma unroll
                for (int r = 0; r < 8; ++r)
                    acc[h * 8 + r][c] = fmaf(w[c].x, xv[r].x, fmaf(w[c].y, xv[r].y,
                                        fmaf(w[c].z, xv[r].z, fmaf(w[c].w, xv[r].w, acc[h * 8 + r][c]))));
        }
#pragma unroll
        for (int c = 0; c < 4; ++c) w[c] = wn[c];
    }
    float bl0 = bl[jg], bl1 = bl[jg + 64];
    float br0 = br[jg], br1 = br[jg + 64];
#pragma unroll
    for (int r = 0; r < 16; ++r) {
        int nn = node0 + r0 + r; if (nn > N_NODES - 1) nn = N_NODES - 1;
        size_t n = (size_t)nn;
        xl[n * D1 + jg]      = acc[r][0] + bl0;
        xl[n * D1 + jg + 64] = acc[r][1] + bl1;
        xr[n * D1 + jg]      = acc[r][2] + br0;
        xr[n * D1 + jg + 64] = acc[r][3] + br1;
    }
}

// ---------- conv2 transform: 128 nodes/block, 16 nodes/thread, 2 cols/thread ----------
__global__ __launch_bounds__(256) void k_transform2(
    const float* __restrict__ hin, const float* __restrict__ wtg,
    const float* __restrict__ bl, const float* __restrict__ br,
    float* __restrict__ xl2, float* __restrict__ xr2)
{
    __shared__ float4 xs[128][32];   // 64 KB
    int node0 = blockIdx.x * 128;
    for (int i = threadIdx.x; i < 4096; i += 256) {
        int r = i >> 5, k4 = i & 31;
        int n = node0 + r; if (n > N_NODES - 1) n = N_NODES - 1;
        xs[r][k4] = *(const float4*)&hin[(size_t)n * D1 + k4 * 4];
    }
    __syncthreads();
    int j  = threadIdx.x & 31;        // output col (L and R side)
    int r0 = (threadIdx.x >> 5) * 16; // 8 groups x 16 nodes = 128
    const float4* __restrict__ wp = (const float4*)wtg;
    float accl[16], accr[16];
#pragma unroll
    for (int r = 0; r < 16; ++r) { accl[r] = 0.f; accr[r] = 0.f; }

    float4 wl_ = wp[j], wr_ = wp[j + 32];

    for (int k4 = 0; k4 < 32; ++k4) {
        int k4n = (k4 < 31) ? k4 + 1 : 31;
        float4 wln = wp[k4n * 64 + j];
        float4 wrn = wp[k4n * 64 + j + 32];
#pragma unroll
        for (int h = 0; h < 2; ++h) {
            float4 xv[8];
#pragma unroll
            for (int r = 0; r < 8; ++r) xv[r] = xs[r0 + h * 8 + r][k4];
#pragma unroll
            for (int r = 0; r < 8; ++r) {
                accl[h * 8 + r] = fmaf(wl_.x, xv[r].x, fmaf(wl_.y, xv[r].y,
                                  fmaf(wl_.z, xv[r].z, fmaf(wl_.w, xv[r].w, accl[h * 8 + r]))));
                accr[h * 8 + r] = fmaf(wr_.x, xv[r].x, fmaf(wr_.y, xv[r].y,
                                  fmaf(wr_.z, xv[r].z, fmaf(wr_.w, xv[r].w, accr[h * 8 + r]))));
            }
        }
        wl_ = wln; wr_ = wrn;
    }
    float bls = bl[j], brs = br[j];
#pragma unroll
    for (int r = 0; r < 16; ++r) {
        int nn = node0 + r0 + r; if (nn > N_NODES - 1) nn = N_NODES - 1;
        size_t n = (size_t)nn;
        xl2[n * HID + j] = accl[r] + bls;
        xr2[n * HID + j] = accr[r] + brs;
    }
}

// ---------- conv1 fused: wave per node, 2 edges/wave, float4 (16B) gathers ----------
__global__ __launch_bounds__(256) void k_gat1_fused(
    const int* __restrict__ rs, const int* __restrict__ csr_src,
    const float* __restrict__ xl, const float* __restrict__ xr,
    const float* __restrict__ att, const float* __restrict__ bias,
    float* __restrict__ hout)
{
    int n = (blockIdx.x * 256 + threadIdx.x) >> 6;
    if (n >= N_NODES) return;
    int lane = threadIdx.x & 63;
    int d0   = lane & 31;
    int half = lane >> 5;
    const float4* xlp = (const float4*)xl;
    float4 r = ((const float4*)xr)[(size_t)n * 32 + d0];
    float4 a = ((const float4*)att)[d0];   // att[h*32 + c] -> float4 index == d0
    float4 l = xlp[(size_t)n * 32 + d0];
    float sc = lrelu_(l.x + r.x) * a.x + lrelu_(l.y + r.y) * a.y
             + lrelu_(l.z + r.z) * a.z + lrelu_(l.w + r.w) * a.w;
    sc += __shfl_xor(sc, 1);
    sc += __shfl_xor(sc, 2);
    sc += __shfl_xor(sc, 4);
    float ex  = (half == 0) ? __expf(sc) : 0.f;
    float den = ex;
    float4 acc = { ex * l.x, ex * l.y, ex * l.z, ex * l.w };
    int e0 = rs[n], e1 = rs[n + 1];
    int p = e0;
    for (; p + 8 <= e1; p += 8) {        // 4 pairs = 8 edges, all valid
        int    sA[4];
        float4 ll[4];
        float  sb[4];
#pragma unroll
        for (int i = 0; i < 4; ++i) sA[i] = csr_src[p + 2 * i + half];
#pragma unroll
        for (int i = 0; i < 4; ++i) ll[i] = xlp[(size_t)sA[i] * 32 + d0];
#pragma unroll
        for (int i = 0; i < 4; ++i)
            sb[i] = lrelu_(ll[i].x + r.x) * a.x + lrelu_(ll[i].y + r.y) * a.y
                  + lrelu_(ll[i].z + r.z) * a.z + lrelu_(ll[i].w + r.w) * a.w;
#pragma unroll
        for (int i = 0; i < 4; ++i) sb[i] += __shfl_xor(sb[i], 1);
#pragma unroll
        for (int i = 0; i < 4; ++i) sb[i] += __shfl_xor(sb[i], 2);
#pragma unroll
        for (int i = 0; i < 4; ++i) sb[i] += __shfl_xor(sb[i], 4);
#pragma unroll
        for (int i = 0; i < 4; ++i) {
            float exx = __expf(sb[i]);
            den   += exx;
            acc.x += exx * ll[i].x;
            acc.y += exx * ll[i].y;
            acc.z += exx * ll[i].z;
            acc.w += exx * ll[i].w;
        }
    }
    for (; p < e1; p += 2) {             // tail pairs, half-validity masked
        int  idx = p + half;
        bool v   = idx < e1;
        int  s   = csr_src[v ? idx : e1 - 1];
        float4 ll = xlp[(size_t)s * 32 + d0];
        float  s1 = lrelu_(ll.x + r.x) * a.x + lrelu_(ll.y + r.y) * a.y
                  + lrelu_(ll.z + r.z) * a.z + lrelu_(ll.w + r.w) * a.w;
        s1 += __shfl_xor(s1, 1);
        s1 += __shfl_xor(s1, 2);
        s1 += __shfl_xor(s1, 4);
        float exx = v ? __expf(s1) : 0.f;
        den   += exx;
        acc.x += exx * ll.x;
        acc.y += exx * ll.y;
        acc.z += exx * ll.z;
        acc.w += exx * ll.w;
    }
    den   += __shfl_xor(den, 32);
    acc.x += __shfl_xor(acc.x, 32);
    acc.y += __shfl_xor(acc.y, 32);
    acc.z += __shfl_xor(acc.z, 32);
    acc.w += __shfl_xor(acc.w, 32);
    if (half == 0) {
        float inv = 1.f / (den + 1e-16f);
        float4 b = ((const float4*)bias)[d0];
        float4 o;
        o.x = elu_(acc.x * inv + b.x);
        o.y = elu_(acc.y * inv + b.y);
        o.z = elu_(acc.z * inv + b.z);
        o.w = elu_(acc.w * inv + b.w);
        ((float4*)hout)[(size_t)n * 32 + d0] = o;   // hout aliases xr: own row only
    }
}

// ---------- conv2 fused: half-wave per node, 4 edges in flight, float4 gathers ----------
__global__ __launch_bounds__(256) void k_gat2_fused(
    const int* __restrict__ rs, const int* __restrict__ csr_src,
    const float* __restrict__ xl2, const float* __restrict__ xr2,
    const float* __restrict__ att, const float* __restrict__ bias,
    float* __restrict__ h2)
{
    int n = (blockIdx.x * 256 + threadIdx.x) >> 5;
    if (n >= N_NODES) return;
    int lane = threadIdx.x & 31;
    int d0   = lane & 7;
    int sub  = lane >> 3;
    const float4* xlp = (const float4*)xl2;
    float4 r = ((const float4*)xr2)[(size_t)n * 8 + d0];
    float4 a = ((const float4*)att)[d0];
    float4 l = xlp[(size_t)n * 8 + d0];
    float sc = lrelu_(l.x + r.x) * a.x + lrelu_(l.y + r.y) * a.y
             + lrelu_(l.z + r.z) * a.z + lrelu_(l.w + r.w) * a.w;
    sc += __shfl_xor(sc, 1);
    sc += __shfl_xor(sc, 2);
    sc += __shfl_xor(sc, 4);
    float ex  = (sub == 0) ? __expf(sc) : 0.f;
    float den = ex;
    float4 acc = { ex * l.x, ex * l.y, ex * l.z, ex * l.w };
    int e0 = rs[n], e1 = rs[n + 1];
    int p = e0;
    for (; p + 16 <= e1; p += 16) {      // 4 quads = 16 edges
        int    sA[4];
        float4 ll[4];
        float  sb[4];
#pragma unroll
        for (int i = 0; i < 4; ++i) sA[i] = csr_src[p + 4 * i + sub];
#pragma unroll
        for (int i = 0; i < 4; ++i) ll[i] = xlp[(size_t)sA[i] * 8 + d0];
#pragma unroll
        for (int i = 0; i < 4; ++i)
            sb[i] = lrelu_(ll[i].x + r.x) * a.x + lrelu_(ll[i].y + r.y) * a.y
                  + lrelu_(ll[i].z + r.z) * a.z + lrelu_(ll[i].w + r.w) * a.w;
#pragma unroll
        for (int i = 0; i < 4; ++i) sb[i] += __shfl_xor(sb[i], 1);
#pragma unroll
        for (int i = 0; i < 4; ++i) sb[i] += __shfl_xor(sb[i], 2);
#pragma unroll
        for (int i = 0; i < 4; ++i) sb[i] += __shfl_xor(sb[i], 4);
#pragma unroll
        for (int i = 0; i < 4; ++i) {
            float exx = __expf(sb[i]);
            den   += exx;
            acc.x += exx * ll[i].x;
            acc.y += exx * ll[i].y;
            acc.z += exx * ll[i].z;
            acc.w += exx * ll[i].w;
        }
    }
    for (; p < e1; p += 4) {             // tail quads, validity masked
        int  idx = p + sub;
        bool v   = idx < e1;
        int  s   = csr_src[v ? idx : e1 - 1];
        float4 ll = xlp[(size_t)s * 8 + d0];
        float  s1 = lrelu_(ll.x + r.x) * a.x + lrelu_(ll.y + r.y) * a.y
                  + lrelu_(ll.z + r.z) * a.z + lrelu_(ll.w + r.w) * a.w;
        s1 += __shfl_xor(s1, 1);
        s1 += __shfl_xor(s1, 2);
        s1 += __shfl_xor(s1, 4);
        float exx = v ? __expf(s1) : 0.f;
        den   += exx;
        acc.x += exx * ll.x;
        acc.y += exx * ll.y;
        acc.z += exx * ll.z;
        acc.w += exx * ll.w;
    }
    den   += __shfl_xor(den, 8);
    den   += __shfl_xor(den, 16);
    acc.x += __shfl_xor(acc.x, 8);  acc.x += __shfl_xor(acc.x, 16);
    acc.y += __shfl_xor(acc.y, 8);  acc.y += __shfl_xor(acc.y, 16);
    acc.z += __shfl_xor(acc.z, 8);  acc.z += __shfl_xor(acc.z, 16);
    acc.w += __shfl_xor(acc.w, 8);  acc.w += __shfl_xor(acc.w, 16);
    if (sub == 0) {
        float inv = 1.f / (den + 1e-16f);
        float4 b = ((const float4*)bias)[d0];
        float4 o;
        o.x = elu_(acc.x * inv + b.x);
        o.y = elu_(acc.y * inv + b.y);
        o.z = elu_(acc.z * inv + b.z);
        o.w = elu_(acc.w * inv + b.w);
        ((float4*)h2)[(size_t)n * 8 + d0] = o;
    }
}

// ---------- per-graph mean pool + both heads ----------
__global__ __launch_bounds__(256) void k_pool_heads(
    const float* __restrict__ h2, const int* __restrict__ gstart,
    const float* __restrict__ wc, const float* __restrict__ bc,
    const float* __restrict__ wp, const float* __restrict__ bp,
    float* __restrict__ out)
{
    int g  = blockIdx.x;
    int n0 = gstart[g], n1 = gstart[g + 1];
    int c    = threadIdx.x & 31;
    int slot = threadIdx.x >> 5;   // 0..7
    float s = 0.f;
    for (int n = n0 + slot; n < n1; n += 8)
        s += h2[n * HID + c];
    __shared__ float red[8][HID];
    red[slot][c] = s;
    __syncthreads();
    if (slot == 0) {
        float tot = 0.f;
#pragma unroll
        for (int i = 0; i < 8; ++i) tot += red[i][c];
        float cntf = fmaxf((float)(n1 - n0), 1.f);
        float p = tot / cntf;
        float sc = p * wc[c];
        float sp = p * wp[c];
        sc += __shfl_xor(sc, 1);  sp += __shfl_xor(sp, 1);
        sc += __shfl_xor(sc, 2);  sp += __shfl_xor(sp, 2);
        sc += __shfl_xor(sc, 4);  sp += __shfl_xor(sp, 4);
        sc += __shfl_xor(sc, 8);  sp += __shfl_xor(sp, 8);
        sc += __shfl_xor(sc, 16); sp += __shfl_xor(sp, 16);
        if (c == 0) {
            out[g]          = sc + bc[0];
            out[NGRAPH + g] = sp + bp[0];
        }
    }
}

extern "C" void kernel_launch(void* const* d_in, const int* in_sizes, int n_in,
                              void* d_out, int out_size, void* d_ws, size_t ws_size,
                              hipStream_t stream)
{
    const float* x     = (const float*)d_in[0];
    const int*   ei    = (const int*)d_in[1];
    const int*   batch = (const int*)d_in[2];
    const float* w1l   = (const float*)d_in[3];
    const float* b1l   = (const float*)d_in[4];
    const float* w1r   = (const float*)d_in[5];
    const float* b1r   = (const float*)d_in[6];
    const float* att1  = (const float*)d_in[7];
    const float* bias1 = (const float*)d_in[8];
    const float* w2l   = (const float*)d_in[9];
    const float* b2l   = (const float*)d_in[10];
    const float* w2r   = (const float*)d_in[11];
    const float* b2r   = (const float*)d_in[12];
    const float* att2  = (const float*)d_in[13];
    const float* bias2 = (const float*)d_in[14];
    const float* wc    = (const float*)d_in[15];
    const float* bc    = (const float*)d_in[16];
    const float* wp    = (const float*)d_in[17];
    const float* bp    = (const float*)d_in[18];
    float* out = (float*)d_out;

    float* ws   = (float*)d_ws;
    // conv1 phase
    float* xl1  = ws;                 // 6,400,000 floats   [0 .. 6.4M)
    float* xr1  = ws + 6400000;       // 6,400,000          [6.4M .. 12.8M)
    float* hbuf = ws + 6400000;       // ALIASES xr1 (safe: per-wave read-own-row-then-write)
    // conv2 phase (xl1 region dead after k_gat1_fused)
    float* xl2  = ws;                 // 1,600,000
    float* xr2  = ws + 1600000;       // 1,600,000
    float* h2   = ws + 3200000;       // 1,600,000
    // int region (after 12.8M floats)
    int* ibase   = (int*)(ws + 12800000);
    int* deg     = ibase;              //  50,000
    int* rs      = ibase + 50000;      //  50,001
    int* cur     = ibase + 100001;     //  50,000
    int* csr_src = ibase + 150001;     // 800,000
    int* gstart  = ibase + 950001;     //      65
    // re-laid-out weights
    float* wtg1 = ws + 13800000;       // 32,768
    float* wtg2 = ws + 13840000;       //  8,192

    // ---- fused prep (wtrans1+wtrans2+zero+gbound), then CSR build ----
    k_prep<<<747, 256, 0, stream>>>(w1l, w1r, wtg1, w2l, w2r, wtg2, deg, cur, batch, gstart);
    k_hist<<<(N_EDGES + 255) / 256, 256, 0, stream>>>(ei, deg);
    k_scan_all<<<1, 1024, 0, stream>>>(deg, rs);
    k_scatter<<<(N_EDGES + 255) / 256, 256, 0, stream>>>(ei, rs, cur, csr_src);

    // ---- conv1 ----
    k_transform1<<<(N_NODES + 63) / 64, 256, 0, stream>>>(x, wtg1, b1l, b1r, xl1, xr1);
    k_gat1_fused<<<(N_NODES * 64 + 255) / 256, 256, 0, stream>>>(rs, csr_src, xl1, xr1, att1, bias1, hbuf);

    // ---- conv2 ----
    k_transform2<<<(N_NODES + 127) / 128, 256, 0, stream>>>(hbuf, wtg2, b2l, b2r, xl2, xr2);
    k_gat2_fused<<<(N_NODES * 32 + 255) / 256, 256, 0, stream>>>(rs, csr_src, xl2, xr2, att2, bias2, h2);

    // ---- pool + heads ----
    k_pool_heads<<<NGRAPH, 256, 0, stream>>>(h2, gstart, wc, bc, wp, bp, out);
}

// Round 5
// 267.148 us; speedup vs baseline: 1.3774x; 1.2399x over previous
//
#include <hip/hip_runtime.h>

#define N_NODES 50000
#define N_EDGES 800000
#define FEATS   128
#define HID     32
#define HEADS   4
#define D1      128      // HEADS*HID
#define NGRAPH  64
#define SCAN_NB ((N_NODES + 1023) / 1024)   // 49

__device__ __forceinline__ float lrelu_(float v) { return v > 0.f ? v : 0.2f * v; }
__device__ __forceinline__ float elu_(float v)   { return v > 0.f ? v : __expf(v) - 1.f; }

typedef __attribute__((ext_vector_type(8))) short short8v;
typedef __attribute__((ext_vector_type(4))) float f32x4;

// fp32 -> bf16 (RNE) high part
__device__ __forceinline__ unsigned short bf16hi_(float x) {
    unsigned u = __float_as_uint(x);
    unsigned r = u + 0x7FFFu + ((u >> 16) & 1);
    return (unsigned short)(r >> 16);
}
__device__ __forceinline__ float bf16f_(unsigned short h) {
    return __uint_as_float(((unsigned)h) << 16);
}

// ---------- CSR build ----------
__global__ __launch_bounds__(256) void k_hist(const int* __restrict__ ei, int* __restrict__ deg)
{
    int e = blockIdx.x * 256 + threadIdx.x;
    if (e < N_EDGES) atomicAdd(&deg[ei[N_EDGES + e]], 1);
}

__global__ __launch_bounds__(1024) void k_scan_local(
    const int* __restrict__ deg, int* __restrict__ rs, int* __restrict__ btot)
{
    __shared__ int sm[1024];
    int idx = blockIdx.x * 1024 + threadIdx.x;
    int v = (idx < N_NODES) ? deg[idx] : 0;
    sm[threadIdx.x] = v;
    __syncthreads();
    for (int off = 1; off < 1024; off <<= 1) {
        int t = (threadIdx.x >= off) ? sm[threadIdx.x - off] : 0;
        __syncthreads();
        sm[threadIdx.x] += t;
        __syncthreads();
    }
    if (idx < N_NODES) rs[idx] = sm[threadIdx.x] - v;   // exclusive
    if (threadIdx.x == 1023) btot[blockIdx.x] = sm[1023];
}

__global__ __launch_bounds__(64) void k_scan_btot(
    const int* __restrict__ btot, int* __restrict__ boff)
{
    int t = threadIdx.x;
    int own = (t < SCAN_NB) ? btot[t] : 0;
    int v = own;
    for (int off = 1; off < 64; off <<= 1) {
        int u = __shfl_up(v, off);
        if (t >= off) v += u;
    }
    if (t < SCAN_NB) boff[t] = v - own;   // exclusive
}

__global__ __launch_bounds__(1024) void k_scan_add(
    int* __restrict__ rs, const int* __restrict__ boff)
{
    int idx = blockIdx.x * 1024 + threadIdx.x;
    if (idx < N_NODES) rs[idx] += boff[blockIdx.x];
    if (idx == N_NODES) rs[N_NODES] = N_EDGES;
}

__global__ __launch_bounds__(256) void k_scatter(const int* __restrict__ ei,
                                                const int* __restrict__ rs,
                                                int* __restrict__ cur,
                                                int* __restrict__ csr_src)
{
    int e = blockIdx.x * 256 + threadIdx.x;
    if (e >= N_EDGES) return;
    int d = ei[N_EDGES + e];
    int p = rs[d] + atomicAdd(&cur[d], 1);
    csr_src[p] = ei[e];
}

__global__ __launch_bounds__(256) void k_gbound(const int* __restrict__ batch, int* __restrict__ gstart)
{
    int i = blockIdx.x * 256 + threadIdx.x;
    if (i > N_NODES) return;
    int b    = (i < N_NODES) ? batch[i] : NGRAPH;
    int prev = (i == 0) ? -1 : batch[i - 1];
    for (int g = prev + 1; g <= b; ++g) gstart[g] = i;
}

// ---------- weight re-layout: conv1 weights -> MFMA-frag-ordered bf16 hi/lo ----------
// frag layout: idx = ((nfrag*4 + ks)*64 + lane)*8 + j
//   col = nfrag*16 + (lane&15); k = ks*32 + ((lane>>4)&3)*8 + j
// B[k][col] = w1l[col][k] (col<128) else w1r[col-128][k]
__global__ __launch_bounds__(256) void k_wtrans1(
    const float* __restrict__ wl, const float* __restrict__ wr,
    unsigned short* __restrict__ bh, unsigned short* __restrict__ blo)
{
    int idx = blockIdx.x * 256 + threadIdx.x;   // 32768
    if (idx >= 32768) return;
    int j    = idx & 7;
    int lane = (idx >> 3) & 63;
    int ks   = (idx >> 9) & 3;
    int nfg  = idx >> 11;                       // 0..15
    int col  = nfg * 16 + (lane & 15);
    int k    = ks * 32 + ((lane >> 4) & 3) * 8 + j;
    float wv = (col < 128) ? wl[col * FEATS + k] : wr[(col - 128) * FEATS + k];
    unsigned short h = bf16hi_(wv);
    float lo = wv - bf16f_(h);
    bh[idx]  = h;
    blo[idx] = bf16hi_(lo);
}

__global__ __launch_bounds__(256) void k_wtrans2(
    const float* __restrict__ wl, const float* __restrict__ wr, float* __restrict__ wtg)
{
    int idx = blockIdx.x * 256 + threadIdx.x;   // 8192
    if (idx >= 32 * 64 * 4) return;
    int kk = idx & 3, j = (idx >> 2) & 63, k4 = idx >> 8;
    int k = k4 * 4 + kk;
    wtg[idx] = (j < 32) ? wl[j * D1 + k] : wr[(j - 32) * D1 + k];
}

// ---------- conv1 transform: MFMA bf16x3, 64 rows/block, wave owns 64 cols ----------
// D[row][col] = sum_k X[row][k]*B[k][col]; X split hi/lo into padded LDS (stride 136 ushort,
// bank offset 4/row -> <=2-way, free); B frags preconverted & frag-ordered (coalesced 16B/lane).
__global__ __launch_bounds__(256) void k_transform1(
    const float* __restrict__ x,
    const unsigned short* __restrict__ bh1, const unsigned short* __restrict__ bl1,
    const float* __restrict__ bl, const float* __restrict__ br,
    float* __restrict__ xl, float* __restrict__ xr)
{
    __shared__ unsigned short XH[64 * 136];   // 17.4 KB
    __shared__ unsigned short XL[64 * 136];   // 17.4 KB
    int m0 = blockIdx.x * 64;
    for (int i = threadIdx.x; i < 2048; i += 256) {      // 64 rows x 32 float4
        int r = i >> 5, c4 = i & 31;
        int n = m0 + r; if (n > N_NODES - 1) n = N_NODES - 1;   // tail clamp (benign dup)
        float4 v = *(const float4*)&x[(size_t)n * FEATS + c4 * 4];
        ushort4 h, lo;
        h.x = bf16hi_(v.x); lo.x = bf16hi_(v.x - bf16f_(h.x));
        h.y = bf16hi_(v.y); lo.y = bf16hi_(v.y - bf16f_(h.y));
        h.z = bf16hi_(v.z); lo.z = bf16hi_(v.z - bf16f_(h.z));
        h.w = bf16hi_(v.w); lo.w = bf16hi_(v.w - bf16f_(h.w));
        *(ushort4*)&XH[r * 136 + c4 * 4] = h;
        *(ushort4*)&XL[r * 136 + c4 * 4] = lo;
    }
    __syncthreads();

    int l  = threadIdx.x & 63;
    int wq = threadIdx.x >> 6;          // wave id = col-quadrant (64 cols)
    int lr = l & 15;
    int lk = (l >> 4) & 3;

    f32x4 acc[4][4];
#pragma unroll
    for (int m = 0; m < 4; ++m)
#pragma unroll
        for (int n = 0; n < 4; ++n)
#pragma unroll
            for (int g = 0; g < 4; ++g) acc[m][n][g] = 0.f;

    const short8v* bhp = (const short8v*)bh1;
    const short8v* blp = (const short8v*)bl1;

#pragma unroll
    for (int ks = 0; ks < 4; ++ks) {
        short8v bh[4], bw[4], ah[4], al[4];
#pragma unroll
        for (int nf = 0; nf < 4; ++nf) {
            int fidx = (((wq * 4 + nf) * 4 + ks) * 64) + l;
            bh[nf] = bhp[fidx];
            bw[nf] = blp[fidx];
        }
#pragma unroll
        for (int mf = 0; mf < 4; ++mf) {
            int off = (mf * 16 + lr) * 136 + ks * 32 + lk * 8;
            ah[mf] = *(const short8v*)&XH[off];
            al[mf] = *(const short8v*)&XL[off];
        }
#pragma unroll
        for (int mf = 0; mf < 4; ++mf)
#pragma unroll
            for (int nf = 0; nf < 4; ++nf) {
                acc[mf][nf] = __builtin_amdgcn_mfma_f32_16x16x32_bf16(ah[mf], bh[nf], acc[mf][nf], 0, 0, 0);
                acc[mf][nf] = __builtin_amdgcn_mfma_f32_16x16x32_bf16(ah[mf], bw[nf], acc[mf][nf], 0, 0, 0);
                acc[mf][nf] = __builtin_amdgcn_mfma_f32_16x16x32_bf16(al[mf], bh[nf], acc[mf][nf], 0, 0, 0);
            }
    }

    // epilogue: D col = lane&15, row = (lane>>4)*4 + reg
#pragma unroll
    for (int nf = 0; nf < 4; ++nf) {
        int col = wq * 64 + nf * 16 + lr;
        float bv   = (col < 128) ? bl[col] : br[col - 128];
        float* dst = (col < 128) ? (xl + col) : (xr + (col - 128));
#pragma unroll
        for (int mf = 0; mf < 4; ++mf)
#pragma unroll
            for (int g = 0; g < 4; ++g) {
                int row = m0 + mf * 16 + lk * 4 + g;
                if (row > N_NODES - 1) row = N_NODES - 1;    // benign dup (same values)
                dst[(size_t)row * D1] = acc[mf][nf][g] + bv;
            }
    }
}

// ---------- conv2 transform: 64 nodes/block, 8 nodes/thread, 2 cols/thread (R2 version) ----------
__global__ __launch_bounds__(256, 2) void k_transform2(
    const float* __restrict__ hin, const float* __restrict__ wtg,
    const float* __restrict__ bl, const float* __restrict__ br,
    float* __restrict__ xl2, float* __restrict__ xr2)
{
    __shared__ float4 xs[64][32];   // 32 KB
    int node0 = blockIdx.x * 64;
    for (int i = threadIdx.x; i < 2048; i += 256) {
        int r = i >> 5, k4 = i & 31;
        int n = node0 + r; if (n > N_NODES - 1) n = N_NODES - 1;
        xs[r][k4] = *(const float4*)&hin[(size_t)n * D1 + k4 * 4];
    }
    __syncthreads();
    int j  = threadIdx.x & 31;
    int r0 = (threadIdx.x >> 5) * 8;
    const float4* __restrict__ wp = (const float4*)wtg;
    float accl[8], accr[8];
#pragma unroll
    for (int r = 0; r < 8; ++r) { accl[r] = 0.f; accr[r] = 0.f; }

    float4 wl_ = wp[j], wr_ = wp[j + 32];

#pragma unroll 2
    for (int k4 = 0; k4 < 32; ++k4) {
        int k4n = (k4 < 31) ? k4 + 1 : 31;
        float4 wln = wp[k4n * 64 + j];
        float4 wrn = wp[k4n * 64 + j + 32];
        float4 xv[8];
#pragma unroll
        for (int r = 0; r < 8; ++r) xv[r] = xs[r0 + r][k4];
#pragma unroll
        for (int r = 0; r < 8; ++r) {
            accl[r] = fmaf(wl_.x, xv[r].x, fmaf(wl_.y, xv[r].y,
                      fmaf(wl_.z, xv[r].z, fmaf(wl_.w, xv[r].w, accl[r]))));
            accr[r] = fmaf(wr_.x, xv[r].x, fmaf(wr_.y, xv[r].y,
                      fmaf(wr_.z, xv[r].z, fmaf(wr_.w, xv[r].w, accr[r]))));
        }
        wl_ = wln; wr_ = wrn;
    }
    float bls = bl[j], brs = br[j];
#pragma unroll
    for (int r = 0; r < 8; ++r) {
        int nn = node0 + r0 + r; if (nn > N_NODES - 1) nn = N_NODES - 1;
        size_t n = (size_t)nn;
        xl2[n * HID + j] = accl[r] + bls;
        xr2[n * HID + j] = accr[r] + brs;
    }
}

// ---------- conv1 fused: wave per node, 2 edges/wave, float4 (16B) gathers ----------
__global__ __launch_bounds__(256) void k_gat1_fused(
    const int* __restrict__ rs, const int* __restrict__ csr_src,
    const float* __restrict__ xl, const float* __restrict__ xr,
    const float* __restrict__ att, const float* __restrict__ bias,
    float* __restrict__ hout)
{
    int n = (blockIdx.x * 256 + threadIdx.x) >> 6;
    if (n >= N_NODES) return;
    int lane = threadIdx.x & 63;
    int d0   = lane & 31;
    int half = lane >> 5;
    const float4* xlp = (const float4*)xl;
    float4 r = ((const float4*)xr)[(size_t)n * 32 + d0];
    float4 a = ((const float4*)att)[d0];
    float4 l = xlp[(size_t)n * 32 + d0];
    float sc = lrelu_(l.x + r.x) * a.x + lrelu_(l.y + r.y) * a.y
             + lrelu_(l.z + r.z) * a.z + lrelu_(l.w + r.w) * a.w;
    sc += __shfl_xor(sc, 1);
    sc += __shfl_xor(sc, 2);
    sc += __shfl_xor(sc, 4);
    float ex  = (half == 0) ? __expf(sc) : 0.f;
    float den = ex;
    float4 acc = { ex * l.x, ex * l.y, ex * l.z, ex * l.w };
    int e0 = rs[n], e1 = rs[n + 1];
    int p = e0;
    for (; p + 8 <= e1; p += 8) {
        int    sA[4];
        float4 ll[4];
        float  sb[4];
#pragma unroll
        for (int i = 0; i < 4; ++i) sA[i] = csr_src[p + 2 * i + half];
#pragma unroll
        for (int i = 0; i < 4; ++i) ll[i] = xlp[(size_t)sA[i] * 32 + d0];
#pragma unroll
        for (int i = 0; i < 4; ++i)
            sb[i] = lrelu_(ll[i].x + r.x) * a.x + lrelu_(ll[i].y + r.y) * a.y
                  + lrelu_(ll[i].z + r.z) * a.z + lrelu_(ll[i].w + r.w) * a.w;
#pragma unroll
        for (int i = 0; i < 4; ++i) sb[i] += __shfl_xor(sb[i], 1);
#pragma unroll
        for (int i = 0; i < 4; ++i) sb[i] += __shfl_xor(sb[i], 2);
#pragma unroll
        for (int i = 0; i < 4; ++i) sb[i] += __shfl_xor(sb[i], 4);
#pragma unroll
        for (int i = 0; i < 4; ++i) {
            float exx = __expf(sb[i]);
            den   += exx;
            acc.x += exx * ll[i].x;
            acc.y += exx * ll[i].y;
            acc.z += exx * ll[i].z;
            acc.w += exx * ll[i].w;
        }
    }
    for (; p < e1; p += 2) {
        int  idx = p + half;
        bool v   = idx < e1;
        int  s   = csr_src[v ? idx : e1 - 1];
        float4 ll = xlp[(size_t)s * 32 + d0];
        float  s1 = lrelu_(ll.x + r.x) * a.x + lrelu_(ll.y + r.y) * a.y
                  + lrelu_(ll.z + r.z) * a.z + lrelu_(ll.w + r.w) * a.w;
        s1 += __shfl_xor(s1, 1);
        s1 += __shfl_xor(s1, 2);
        s1 += __shfl_xor(s1, 4);
        float exx = v ? __expf(s1) : 0.f;
        den   += exx;
        acc.x += exx * ll.x;
        acc.y += exx * ll.y;
        acc.z += exx * ll.z;
        acc.w += exx * ll.w;
    }
    den   += __shfl_xor(den, 32);
    acc.x += __shfl_xor(acc.x, 32);
    acc.y += __shfl_xor(acc.y, 32);
    acc.z += __shfl_xor(acc.z, 32);
    acc.w += __shfl_xor(acc.w, 32);
    if (half == 0) {
        float inv = 1.f / (den + 1e-16f);
        float4 b = ((const float4*)bias)[d0];
        float4 o;
        o.x = elu_(acc.x * inv + b.x);
        o.y = elu_(acc.y * inv + b.y);
        o.z = elu_(acc.z * inv + b.z);
        o.w = elu_(acc.w * inv + b.w);
        ((float4*)hout)[(size_t)n * 32 + d0] = o;   // hout aliases xr: own row only
    }
}

// ---------- conv2 fused: half-wave per node, 4 edges in flight, float4 gathers ----------
__global__ __launch_bounds__(256) void k_gat2_fused(
    const int* __restrict__ rs, const int* __restrict__ csr_src,
    const float* __restrict__ xl2, const float* __restrict__ xr2,
    const float* __restrict__ att, const float* __restrict__ bias,
    float* __restrict__ h2)
{
    int n = (blockIdx.x * 256 + threadIdx.x) >> 5;
    if (n >= N_NODES) return;
    int lane = threadIdx.x & 31;
    int d0   = lane & 7;
    int sub  = lane >> 3;
    const float4* xlp = (const float4*)xl2;
    float4 r = ((const float4*)xr2)[(size_t)n * 8 + d0];
    float4 a = ((const float4*)att)[d0];
    float4 l = xlp[(size_t)n * 8 + d0];
    float sc = lrelu_(l.x + r.x) * a.x + lrelu_(l.y + r.y) * a.y
             + lrelu_(l.z + r.z) * a.z + lrelu_(l.w + r.w) * a.w;
    sc += __shfl_xor(sc, 1);
    sc += __shfl_xor(sc, 2);
    sc += __shfl_xor(sc, 4);
    float ex  = (sub == 0) ? __expf(sc) : 0.f;
    float den = ex;
    float4 acc = { ex * l.x, ex * l.y, ex * l.z, ex * l.w };
    int e0 = rs[n], e1 = rs[n + 1];
    int p = e0;
    for (; p + 16 <= e1; p += 16) {
        int    sA[4];
        float4 ll[4];
        float  sb[4];
#pragma unroll
        for (int i = 0; i < 4; ++i) sA[i] = csr_src[p + 4 * i + sub];
#pragma unroll
        for (int i = 0; i < 4; ++i) ll[i] = xlp[(size_t)sA[i] * 8 + d0];
#pragma unroll
        for (int i = 0; i < 4; ++i)
            sb[i] = lrelu_(ll[i].x + r.x) * a.x + lrelu_(ll[i].y + r.y) * a.y
                  + lrelu_(ll[i].z + r.z) * a.z + lrelu_(ll[i].w + r.w) * a.w;
#pragma unroll
        for (int i = 0; i < 4; ++i) sb[i] += __shfl_xor(sb[i], 1);
#pragma unroll
        for (int i = 0; i < 4; ++i) sb[i] += __shfl_xor(sb[i], 2);
#pragma unroll
        for (int i = 0; i < 4; ++i) sb[i] += __shfl_xor(sb[i], 4);
#pragma unroll
        for (int i = 0; i < 4; ++i) {
            float exx = __expf(sb[i]);
            den   += exx;
            acc.x += exx * ll[i].x;
            acc.y += exx * ll[i].y;
            acc.z += exx * ll[i].z;
            acc.w += exx * ll[i].w;
        }
    }
    for (; p < e1; p += 4) {
        int  idx = p + sub;
        bool v   = idx < e1;
        int  s   = csr_src[v ? idx : e1 - 1];
        float4 ll = xlp[(size_t)s * 8 + d0];
        float  s1 = lrelu_(ll.x + r.x) * a.x + lrelu_(ll.y + r.y) * a.y
                  + lrelu_(ll.z + r.z) * a.z + lrelu_(ll.w + r.w) * a.w;
        s1 += __shfl_xor(s1, 1);
        s1 += __shfl_xor(s1, 2);
        s1 += __shfl_xor(s1, 4);
        float exx = v ? __expf(s1) : 0.f;
        den   += exx;
        acc.x += exx * ll.x;
        acc.y += exx * ll.y;
        acc.z += exx * ll.z;
        acc.w += exx * ll.w;
    }
    den   += __shfl_xor(den, 8);
    den   += __shfl_xor(den, 16);
    acc.x += __shfl_xor(acc.x, 8);  acc.x += __shfl_xor(acc.x, 16);
    acc.y += __shfl_xor(acc.y, 8);  acc.y += __shfl_xor(acc.y, 16);
    acc.z += __shfl_xor(acc.z, 8);  acc.z += __shfl_xor(acc.z, 16);
    acc.w += __shfl_xor(acc.w, 8);  acc.w += __shfl_xor(acc.w, 16);
    if (sub == 0) {
        float inv = 1.f / (den + 1e-16f);
        float4 b = ((const float4*)bias)[d0];
        float4 o;
        o.x = elu_(acc.x * inv + b.x);
        o.y = elu_(acc.y * inv + b.y);
        o.z = elu_(acc.z * inv + b.z);
        o.w = elu_(acc.w * inv + b.w);
        ((float4*)h2)[(size_t)n * 8 + d0] = o;
    }
}

// ---------- per-graph mean pool + both heads ----------
__global__ __launch_bounds__(256) void k_pool_heads(
    const float* __restrict__ h2, const int* __restrict__ gstart,
    const float* __restrict__ wc, const float* __restrict__ bc,
    const float* __restrict__ wp, const float* __restrict__ bp,
    float* __restrict__ out)
{
    int g  = blockIdx.x;
    int n0 = gstart[g], n1 = gstart[g + 1];
    int c    = threadIdx.x & 31;
    int slot = threadIdx.x >> 5;   // 0..7
    float s = 0.f;
    for (int n = n0 + slot; n < n1; n += 8)
        s += h2[n * HID + c];
    __shared__ float red[8][HID];
    red[slot][c] = s;
    __syncthreads();
    if (slot == 0) {
        float tot = 0.f;
#pragma unroll
        for (int i = 0; i < 8; ++i) tot += red[i][c];
        float cntf = fmaxf((float)(n1 - n0), 1.f);
        float p = tot / cntf;
        float sc = p * wc[c];
        float sp = p * wp[c];
        sc += __shfl_xor(sc, 1);  sp += __shfl_xor(sp, 1);
        sc += __shfl_xor(sc, 2);  sp += __shfl_xor(sp, 2);
        sc += __shfl_xor(sc, 4);  sp += __shfl_xor(sp, 4);
        sc += __shfl_xor(sc, 8);  sp += __shfl_xor(sp, 8);
        sc += __shfl_xor(sc, 16); sp += __shfl_xor(sp, 16);
        if (c == 0) {
            out[g]          = sc + bc[0];
            out[NGRAPH + g] = sp + bp[0];
        }
    }
}

extern "C" void kernel_launch(void* const* d_in, const int* in_sizes, int n_in,
                              void* d_out, int out_size, void* d_ws, size_t ws_size,
                              hipStream_t stream)
{
    const float* x     = (const float*)d_in[0];
    const int*   ei    = (const int*)d_in[1];
    const int*   batch = (const int*)d_in[2];
    const float* w1l   = (const float*)d_in[3];
    const float* b1l   = (const float*)d_in[4];
    const float* w1r   = (const float*)d_in[5];
    const float* b1r   = (const float*)d_in[6];
    const float* att1  = (const float*)d_in[7];
    const float* bias1 = (const float*)d_in[8];
    const float* w2l   = (const float*)d_in[9];
    const float* b2l   = (const float*)d_in[10];
    const float* w2r   = (const float*)d_in[11];
    const float* b2r   = (const float*)d_in[12];
    const float* att2  = (const float*)d_in[13];
    const float* bias2 = (const float*)d_in[14];
    const float* wc    = (const float*)d_in[15];
    const float* bc    = (const float*)d_in[16];
    const float* wp    = (const float*)d_in[17];
    const float* bp    = (const float*)d_in[18];
    float* out = (float*)d_out;

    float* ws   = (float*)d_ws;
    // conv1 phase
    float* xl1  = ws;                 // 6,400,000 floats   [0 .. 6.4M)
    float* xr1  = ws + 6400000;       // 6,400,000          [6.4M .. 12.8M)
    float* hbuf = ws + 6400000;       // ALIASES xr1 (safe: per-wave read-own-row-then-write)
    // conv2 phase (xl1 region dead after k_gat1_fused)
    float* xl2  = ws;                 // 1,600,000
    float* xr2  = ws + 1600000;       // 1,600,000
    float* h2   = ws + 3200000;       // 1,600,000
    // int region (after 12.8M floats)
    int* ibase   = (int*)(ws + 12800000);
    int* deg     = ibase;              //  50,000
    int* rs      = ibase + 50000;      //  50,001
    int* cur     = ibase + 100001;     //  50,000
    int* csr_src = ibase + 150001;     // 800,000
    int* gstart  = ibase + 950001;     //      65
    int* btot    = ibase + 950101;     //      49
    int* boff    = ibase + 950151;     //      49
    // re-laid-out weights: conv1 bf16 hi/lo frag-order (reuses old wtg1 region), conv2 fp32
    unsigned short* bh1 = (unsigned short*)(ws + 13800000);   // 32768 ushort
    unsigned short* bl1_ = (unsigned short*)(ws + 13816384);  // 32768 ushort
    float* wtg2 = ws + 13840000;       //  8,192 floats

    // ---- one-time weight re-layout + CSR build + graph boundaries ----
    k_wtrans1<<<128, 256, 0, stream>>>(w1l, w1r, bh1, bl1_);
    k_wtrans2<<<32, 256, 0, stream>>>(w2l, w2r, wtg2);
    hipMemsetAsync(deg, 0, N_NODES * sizeof(int), stream);
    hipMemsetAsync(cur, 0, N_NODES * sizeof(int), stream);
    k_hist<<<(N_EDGES + 255) / 256, 256, 0, stream>>>(ei, deg);
    k_scan_local<<<SCAN_NB, 1024, 0, stream>>>(deg, rs, btot);
    k_scan_btot<<<1, 64, 0, stream>>>(btot, boff);
    k_scan_add<<<SCAN_NB, 1024, 0, stream>>>(rs, boff);
    k_scatter<<<(N_EDGES + 255) / 256, 256, 0, stream>>>(ei, rs, cur, csr_src);
    k_gbound<<<(N_NODES + 1 + 255) / 256, 256, 0, stream>>>(batch, gstart);

    // ---- conv1 ----
    k_transform1<<<(N_NODES + 63) / 64, 256, 0, stream>>>(x, bh1, bl1_, b1l, b1r, xl1, xr1);
    k_gat1_fused<<<(N_NODES * 64 + 255) / 256, 256, 0, stream>>>(rs, csr_src, xl1, xr1, att1, bias1, hbuf);

    // ---- conv2 ----
    k_transform2<<<(N_NODES + 63) / 64, 256, 0, stream>>>(hbuf, wtg2, b2l, b2r, xl2, xr2);
    k_gat2_fused<<<(N_NODES * 32 + 255) / 256, 256, 0, stream>>>(rs, csr_src, xl2, xr2, att2, bias2, h2);

    // ---- pool + heads ----
    k_pool_heads<<<NGRAPH, 256, 0, stream>>>(h2, gstart, wc, bc, wp, bp, out);
}

// Round 6
// 243.029 us; speedup vs baseline: 1.5141x; 1.0992x over previous
//
#include <hip/hip_runtime.h>

#define N_NODES 50000
#define N_EDGES 800000
#define FEATS   128
#define HID     32
#define HEADS   4
#define D1      128      // HEADS*HID
#define NGRAPH  64
#define SCAN_NB ((N_NODES + 1023) / 1024)   // 49

__device__ __forceinline__ float lrelu_(float v) { return v > 0.f ? v : 0.2f * v; }
__device__ __forceinline__ float elu_(float v)   { return v > 0.f ? v : __expf(v) - 1.f; }

typedef __attribute__((ext_vector_type(8))) short short8v;
typedef __attribute__((ext_vector_type(4))) float f32x4;

// fp32 -> bf16 (RNE) high part
__device__ __forceinline__ unsigned short bf16hi_(float x) {
    unsigned u = __float_as_uint(x);
    unsigned r = u + 0x7FFFu + ((u >> 16) & 1);
    return (unsigned short)(r >> 16);
}
__device__ __forceinline__ float bf16f_(unsigned short h) {
    return __uint_as_float(((unsigned)h) << 16);
}
__device__ __forceinline__ float4 b2f4_(ushort4 u) {
    float4 f;
    f.x = __uint_as_float(((unsigned)u.x) << 16);
    f.y = __uint_as_float(((unsigned)u.y) << 16);
    f.z = __uint_as_float(((unsigned)u.z) << 16);
    f.w = __uint_as_float(((unsigned)u.w) << 16);
    return f;
}

// ---------- CSR build ----------
__global__ __launch_bounds__(256) void k_hist(const int* __restrict__ ei, int* __restrict__ deg)
{
    int e = blockIdx.x * 256 + threadIdx.x;
    if (e < N_EDGES) atomicAdd(&deg[ei[N_EDGES + e]], 1);
}

__global__ __launch_bounds__(1024) void k_scan_local(
    const int* __restrict__ deg, int* __restrict__ rs, int* __restrict__ btot)
{
    __shared__ int sm[1024];
    int idx = blockIdx.x * 1024 + threadIdx.x;
    int v = (idx < N_NODES) ? deg[idx] : 0;
    sm[threadIdx.x] = v;
    __syncthreads();
    for (int off = 1; off < 1024; off <<= 1) {
        int t = (threadIdx.x >= off) ? sm[threadIdx.x - off] : 0;
        __syncthreads();
        sm[threadIdx.x] += t;
        __syncthreads();
    }
    if (idx < N_NODES) rs[idx] = sm[threadIdx.x] - v;   // exclusive
    if (threadIdx.x == 1023) btot[blockIdx.x] = sm[1023];
}

__global__ __launch_bounds__(64) void k_scan_btot(
    const int* __restrict__ btot, int* __restrict__ boff)
{
    int t = threadIdx.x;
    int own = (t < SCAN_NB) ? btot[t] : 0;
    int v = own;
    for (int off = 1; off < 64; off <<= 1) {
        int u = __shfl_up(v, off);
        if (t >= off) v += u;
    }
    if (t < SCAN_NB) boff[t] = v - own;   // exclusive
}

__global__ __launch_bounds__(1024) void k_scan_add(
    int* __restrict__ rs, const int* __restrict__ boff)
{
    int idx = blockIdx.x * 1024 + threadIdx.x;
    if (idx < N_NODES) rs[idx] += boff[blockIdx.x];
    if (idx == N_NODES) rs[N_NODES] = N_EDGES;
}

__global__ __launch_bounds__(256) void k_scatter(const int* __restrict__ ei,
                                                const int* __restrict__ rs,
                                                int* __restrict__ cur,
                                                int* __restrict__ csr_src)
{
    int e = blockIdx.x * 256 + threadIdx.x;
    if (e >= N_EDGES) return;
    int d = ei[N_EDGES + e];
    int p = rs[d] + atomicAdd(&cur[d], 1);
    csr_src[p] = ei[e];
}

__global__ __launch_bounds__(256) void k_gbound(const int* __restrict__ batch, int* __restrict__ gstart)
{
    int i = blockIdx.x * 256 + threadIdx.x;
    if (i > N_NODES) return;
    int b    = (i < N_NODES) ? batch[i] : NGRAPH;
    int prev = (i == 0) ? -1 : batch[i - 1];
    for (int g = prev + 1; g <= b; ++g) gstart[g] = i;
}

// ---------- weight re-layout: conv1 weights -> MFMA-frag-ordered bf16 hi/lo ----------
__global__ __launch_bounds__(256) void k_wtrans1(
    const float* __restrict__ wl, const float* __restrict__ wr,
    unsigned short* __restrict__ bh, unsigned short* __restrict__ blo)
{
    int idx = blockIdx.x * 256 + threadIdx.x;   // 32768
    if (idx >= 32768) return;
    int j    = idx & 7;
    int lane = (idx >> 3) & 63;
    int ks   = (idx >> 9) & 3;
    int nfg  = idx >> 11;                       // 0..15
    int col  = nfg * 16 + (lane & 15);
    int k    = ks * 32 + ((lane >> 4) & 3) * 8 + j;
    float wv = (col < 128) ? wl[col * FEATS + k] : wr[(col - 128) * FEATS + k];
    unsigned short h = bf16hi_(wv);
    float lo = wv - bf16f_(h);
    bh[idx]  = h;
    blo[idx] = bf16hi_(lo);
}

__global__ __launch_bounds__(256) void k_wtrans2(
    const float* __restrict__ wl, const float* __restrict__ wr, float* __restrict__ wtg)
{
    int idx = blockIdx.x * 256 + threadIdx.x;   // 8192
    if (idx >= 32 * 64 * 4) return;
    int kk = idx & 3, j = (idx >> 2) & 63, k4 = idx >> 8;
    int k = k4 * 4 + kk;
    wtg[idx] = (j < 32) ? wl[j * D1 + k] : wr[(j - 32) * D1 + k];
}

// ---------- conv1 transform: MFMA bf16x3, 64 rows/block, wave owns 64 cols ----------
// xl output now bf16 (gathered table); xr stays fp32 (own-row reads only).
__global__ __launch_bounds__(256) void k_transform1(
    const float* __restrict__ x,
    const unsigned short* __restrict__ bh1, const unsigned short* __restrict__ bl1,
    const float* __restrict__ bl, const float* __restrict__ br,
    unsigned short* __restrict__ xlb, float* __restrict__ xr)
{
    __shared__ unsigned short XH[64 * 136];   // 17.4 KB
    __shared__ unsigned short XL[64 * 136];   // 17.4 KB
    int m0 = blockIdx.x * 64;
    for (int i = threadIdx.x; i < 2048; i += 256) {      // 64 rows x 32 float4
        int r = i >> 5, c4 = i & 31;
        int n = m0 + r; if (n > N_NODES - 1) n = N_NODES - 1;   // tail clamp (benign dup)
        float4 v = *(const float4*)&x[(size_t)n * FEATS + c4 * 4];
        ushort4 h, lo;
        h.x = bf16hi_(v.x); lo.x = bf16hi_(v.x - bf16f_(h.x));
        h.y = bf16hi_(v.y); lo.y = bf16hi_(v.y - bf16f_(h.y));
        h.z = bf16hi_(v.z); lo.z = bf16hi_(v.z - bf16f_(h.z));
        h.w = bf16hi_(v.w); lo.w = bf16hi_(v.w - bf16f_(h.w));
        *(ushort4*)&XH[r * 136 + c4 * 4] = h;
        *(ushort4*)&XL[r * 136 + c4 * 4] = lo;
    }
    __syncthreads();

    int l  = threadIdx.x & 63;
    int wq = threadIdx.x >> 6;          // wave id = col-quadrant (64 cols)
    int lr = l & 15;
    int lk = (l >> 4) & 3;

    f32x4 acc[4][4];
#pragma unroll
    for (int m = 0; m < 4; ++m)
#pragma unroll
        for (int n = 0; n < 4; ++n)
#pragma unroll
            for (int g = 0; g < 4; ++g) acc[m][n][g] = 0.f;

    const short8v* bhp = (const short8v*)bh1;
    const short8v* blp = (const short8v*)bl1;

#pragma unroll
    for (int ks = 0; ks < 4; ++ks) {
        short8v bh[4], bw[4], ah[4], al[4];
#pragma unroll
        for (int nf = 0; nf < 4; ++nf) {
            int fidx = (((wq * 4 + nf) * 4 + ks) * 64) + l;
            bh[nf] = bhp[fidx];
            bw[nf] = blp[fidx];
        }
#pragma unroll
        for (int mf = 0; mf < 4; ++mf) {
            int off = (mf * 16 + lr) * 136 + ks * 32 + lk * 8;
            ah[mf] = *(const short8v*)&XH[off];
            al[mf] = *(const short8v*)&XL[off];
        }
#pragma unroll
        for (int mf = 0; mf < 4; ++mf)
#pragma unroll
            for (int nf = 0; nf < 4; ++nf) {
                acc[mf][nf] = __builtin_amdgcn_mfma_f32_16x16x32_bf16(ah[mf], bh[nf], acc[mf][nf], 0, 0, 0);
                acc[mf][nf] = __builtin_amdgcn_mfma_f32_16x16x32_bf16(ah[mf], bw[nf], acc[mf][nf], 0, 0, 0);
                acc[mf][nf] = __builtin_amdgcn_mfma_f32_16x16x32_bf16(al[mf], bh[nf], acc[mf][nf], 0, 0, 0);
            }
    }

    // epilogue: D col = lane&15, row = (lane>>4)*4 + reg
#pragma unroll
    for (int nf = 0; nf < 4; ++nf) {
        int col = wq * 64 + nf * 16 + lr;
        float bv = (col < 128) ? bl[col] : br[col - 128];
#pragma unroll
        for (int mf = 0; mf < 4; ++mf)
#pragma unroll
            for (int g = 0; g < 4; ++g) {
                int row = m0 + mf * 16 + lk * 4 + g;
                if (row > N_NODES - 1) row = N_NODES - 1;    // benign dup (same values)
                float v = acc[mf][nf][g] + bv;
                if (col < 128) xlb[(size_t)row * 128 + col] = bf16hi_(v);
                else           xr [(size_t)row * D1 + (col - 128)] = v;
            }
    }
}

// ---------- conv2 transform: 64 nodes/block, 8 nodes/thread, 2 cols/thread ----------
// xl2 output now bf16 (gathered table); xr2 stays fp32.
__global__ __launch_bounds__(256, 2) void k_transform2(
    const float* __restrict__ hin, const float* __restrict__ wtg,
    const float* __restrict__ bl, const float* __restrict__ br,
    unsigned short* __restrict__ xlb2, float* __restrict__ xr2)
{
    __shared__ float4 xs[64][32];   // 32 KB
    int node0 = blockIdx.x * 64;
    for (int i = threadIdx.x; i < 2048; i += 256) {
        int r = i >> 5, k4 = i & 31;
        int n = node0 + r; if (n > N_NODES - 1) n = N_NODES - 1;
        xs[r][k4] = *(const float4*)&hin[(size_t)n * D1 + k4 * 4];
    }
    __syncthreads();
    int j  = threadIdx.x & 31;
    int r0 = (threadIdx.x >> 5) * 8;
    const float4* __restrict__ wp = (const float4*)wtg;
    float accl[8], accr[8];
#pragma unroll
    for (int r = 0; r < 8; ++r) { accl[r] = 0.f; accr[r] = 0.f; }

    float4 wl_ = wp[j], wr_ = wp[j + 32];

#pragma unroll 2
    for (int k4 = 0; k4 < 32; ++k4) {
        int k4n = (k4 < 31) ? k4 + 1 : 31;
        float4 wln = wp[k4n * 64 + j];
        float4 wrn = wp[k4n * 64 + j + 32];
        float4 xv[8];
#pragma unroll
        for (int r = 0; r < 8; ++r) xv[r] = xs[r0 + r][k4];
#pragma unroll
        for (int r = 0; r < 8; ++r) {
            accl[r] = fmaf(wl_.x, xv[r].x, fmaf(wl_.y, xv[r].y,
                      fmaf(wl_.z, xv[r].z, fmaf(wl_.w, xv[r].w, accl[r]))));
            accr[r] = fmaf(wr_.x, xv[r].x, fmaf(wr_.y, xv[r].y,
                      fmaf(wr_.z, xv[r].z, fmaf(wr_.w, xv[r].w, accr[r]))));
        }
        wl_ = wln; wr_ = wrn;
    }
    float bls = bl[j], brs = br[j];
#pragma unroll
    for (int r = 0; r < 8; ++r) {
        int nn = node0 + r0 + r; if (nn > N_NODES - 1) nn = N_NODES - 1;
        size_t n = (size_t)nn;
        xlb2[n * HID + j] = bf16hi_(accl[r] + bls);
        xr2 [n * HID + j] = accr[r] + brs;
    }
}

// ---------- conv1 fused: wave per node, 2 edges/wave, bf16 ushort4 (8B) gathers ----------
__global__ __launch_bounds__(256) void k_gat1_fused(
    const int* __restrict__ rs, const int* __restrict__ csr_src,
    const unsigned short* __restrict__ xlb, const float* __restrict__ xr,
    const float* __restrict__ att, const float* __restrict__ bias,
    float* __restrict__ hout)
{
    int n = (blockIdx.x * 256 + threadIdx.x) >> 6;
    if (n >= N_NODES) return;
    int lane = threadIdx.x & 63;
    int d0   = lane & 31;
    int half = lane >> 5;
    const ushort4* xlp = (const ushort4*)xlb;
    float4 r = ((const float4*)xr)[(size_t)n * 32 + d0];
    float4 a = ((const float4*)att)[d0];
    float4 l = b2f4_(xlp[(size_t)n * 32 + d0]);
    float sc = lrelu_(l.x + r.x) * a.x + lrelu_(l.y + r.y) * a.y
             + lrelu_(l.z + r.z) * a.z + lrelu_(l.w + r.w) * a.w;
    sc += __shfl_xor(sc, 1);
    sc += __shfl_xor(sc, 2);
    sc += __shfl_xor(sc, 4);
    float ex  = (half == 0) ? __expf(sc) : 0.f;
    float den = ex;
    float4 acc = { ex * l.x, ex * l.y, ex * l.z, ex * l.w };
    int e0 = rs[n], e1 = rs[n + 1];
    int p = e0;
    for (; p + 8 <= e1; p += 8) {
        int    sA[4];
        ushort4 lu[4];
        float4 ll[4];
        float  sb[4];
#pragma unroll
        for (int i = 0; i < 4; ++i) sA[i] = csr_src[p + 2 * i + half];
#pragma unroll
        for (int i = 0; i < 4; ++i) lu[i] = xlp[(size_t)sA[i] * 32 + d0];
#pragma unroll
        for (int i = 0; i < 4; ++i) ll[i] = b2f4_(lu[i]);
#pragma unroll
        for (int i = 0; i < 4; ++i)
            sb[i] = lrelu_(ll[i].x + r.x) * a.x + lrelu_(ll[i].y + r.y) * a.y
                  + lrelu_(ll[i].z + r.z) * a.z + lrelu_(ll[i].w + r.w) * a.w;
#pragma unroll
        for (int i = 0; i < 4; ++i) sb[i] += __shfl_xor(sb[i], 1);
#pragma unroll
        for (int i = 0; i < 4; ++i) sb[i] += __shfl_xor(sb[i], 2);
#pragma unroll
        for (int i = 0; i < 4; ++i) sb[i] += __shfl_xor(sb[i], 4);
#pragma unroll
        for (int i = 0; i < 4; ++i) {
            float exx = __expf(sb[i]);
            den   += exx;
            acc.x += exx * ll[i].x;
            acc.y += exx * ll[i].y;
            acc.z += exx * ll[i].z;
            acc.w += exx * ll[i].w;
        }
    }
    for (; p < e1; p += 2) {
        int  idx = p + half;
        bool v   = idx < e1;
        int  s   = csr_src[v ? idx : e1 - 1];
        float4 ll = b2f4_(xlp[(size_t)s * 32 + d0]);
        float  s1 = lrelu_(ll.x + r.x) * a.x + lrelu_(ll.y + r.y) * a.y
                  + lrelu_(ll.z + r.z) * a.z + lrelu_(ll.w + r.w) * a.w;
        s1 += __shfl_xor(s1, 1);
        s1 += __shfl_xor(s1, 2);
        s1 += __shfl_xor(s1, 4);
        float exx = v ? __expf(s1) : 0.f;
        den   += exx;
        acc.x += exx * ll.x;
        acc.y += exx * ll.y;
        acc.z += exx * ll.z;
        acc.w += exx * ll.w;
    }
    den   += __shfl_xor(den, 32);
    acc.x += __shfl_xor(acc.x, 32);
    acc.y += __shfl_xor(acc.y, 32);
    acc.z += __shfl_xor(acc.z, 32);
    acc.w += __shfl_xor(acc.w, 32);
    if (half == 0) {
        float inv = 1.f / (den + 1e-16f);
        float4 b = ((const float4*)bias)[d0];
        float4 o;
        o.x = elu_(acc.x * inv + b.x);
        o.y = elu_(acc.y * inv + b.y);
        o.z = elu_(acc.z * inv + b.z);
        o.w = elu_(acc.w * inv + b.w);
        ((float4*)hout)[(size_t)n * 32 + d0] = o;   // hout aliases xr: own row only
    }
}

// ---------- conv2 fused: half-wave per node, 4 edges in flight, bf16 gathers ----------
__global__ __launch_bounds__(256) void k_gat2_fused(
    const int* __restrict__ rs, const int* __restrict__ csr_src,
    const unsigned short* __restrict__ xlb2, const float* __restrict__ xr2,
    const float* __restrict__ att, const float* __restrict__ bias,
    float* __restrict__ h2)
{
    int n = (blockIdx.x * 256 + threadIdx.x) >> 5;
    if (n >= N_NODES) return;
    int lane = threadIdx.x & 31;
    int d0   = lane & 7;
    int sub  = lane >> 3;
    const ushort4* xlp = (const ushort4*)xlb2;
    float4 r = ((const float4*)xr2)[(size_t)n * 8 + d0];
    float4 a = ((const float4*)att)[d0];
    float4 l = b2f4_(xlp[(size_t)n * 8 + d0]);
    float sc = lrelu_(l.x + r.x) * a.x + lrelu_(l.y + r.y) * a.y
             + lrelu_(l.z + r.z) * a.z + lrelu_(l.w + r.w) * a.w;
    sc += __shfl_xor(sc, 1);
    sc += __shfl_xor(sc, 2);
    sc += __shfl_xor(sc, 4);
    float ex  = (sub == 0) ? __expf(sc) : 0.f;
    float den = ex;
    float4 acc = { ex * l.x, ex * l.y, ex * l.z, ex * l.w };
    int e0 = rs[n], e1 = rs[n + 1];
    int p = e0;
    for (; p + 16 <= e1; p += 16) {
        int    sA[4];
        ushort4 lu[4];
        float4 ll[4];
        float  sb[4];
#pragma unroll
        for (int i = 0; i < 4; ++i) sA[i] = csr_src[p + 4 * i + sub];
#pragma unroll
        for (int i = 0; i < 4; ++i) lu[i] = xlp[(size_t)sA[i] * 8 + d0];
#pragma unroll
        for (int i = 0; i < 4; ++i) ll[i] = b2f4_(lu[i]);
#pragma unroll
        for (int i = 0; i < 4; ++i)
            sb[i] = lrelu_(ll[i].x + r.x) * a.x + lrelu_(ll[i].y + r.y) * a.y
                  + lrelu_(ll[i].z + r.z) * a.z + lrelu_(ll[i].w + r.w) * a.w;
#pragma unroll
        for (int i = 0; i < 4; ++i) sb[i] += __shfl_xor(sb[i], 1);
#pragma unroll
        for (int i = 0; i < 4; ++i) sb[i] += __shfl_xor(sb[i], 2);
#pragma unroll
        for (int i = 0; i < 4; ++i) sb[i] += __shfl_xor(sb[i], 4);
#pragma unroll
        for (int i = 0; i < 4; ++i) {
            float exx = __expf(sb[i]);
            den   += exx;
            acc.x += exx * ll[i].x;
            acc.y += exx * ll[i].y;
            acc.z += exx * ll[i].z;
            acc.w += exx * ll[i].w;
        }
    }
    for (; p < e1; p += 4) {
        int  idx = p + sub;
        bool v   = idx < e1;
        int  s   = csr_src[v ? idx : e1 - 1];
        float4 ll = b2f4_(xlp[(size_t)s * 8 + d0]);
        float  s1 = lrelu_(ll.x + r.x) * a.x + lrelu_(ll.y + r.y) * a.y
                  + lrelu_(ll.z + r.z) * a.z + lrelu_(ll.w + r.w) * a.w;
        s1 += __shfl_xor(s1, 1);
        s1 += __shfl_xor(s1, 2);
        s1 += __shfl_xor(s1, 4);
        float exx = v ? __expf(s1) : 0.f;
        den   += exx;
        acc.x += exx * ll.x;
        acc.y += exx * ll.y;
        acc.z += exx * ll.z;
        acc.w += exx * ll.w;
    }
    den   += __shfl_xor(den, 8);
    den   += __shfl_xor(den, 16);
    acc.x += __shfl_xor(acc.x, 8);  acc.x += __shfl_xor(acc.x, 16);
    acc.y += __shfl_xor(acc.y, 8);  acc.y += __shfl_xor(acc.y, 16);
    acc.z += __shfl_xor(acc.z, 8);  acc.z += __shfl_xor(acc.z, 16);
    acc.w += __shfl_xor(acc.w, 8);  acc.w += __shfl_xor(acc.w, 16);
    if (sub == 0) {
        float inv = 1.f / (den + 1e-16f);
        float4 b = ((const float4*)bias)[d0];
        float4 o;
        o.x = elu_(acc.x * inv + b.x);
        o.y = elu_(acc.y * inv + b.y);
        o.z = elu_(acc.z * inv + b.z);
        o.w = elu_(acc.w * inv + b.w);
        ((float4*)h2)[(size_t)n * 8 + d0] = o;
    }
}

// ---------- per-graph mean pool + both heads ----------
__global__ __launch_bounds__(256) void k_pool_heads(
    const float* __restrict__ h2, const int* __restrict__ gstart,
    const float* __restrict__ wc, const float* __restrict__ bc,
    const float* __restrict__ wp, const float* __restrict__ bp,
    float* __restrict__ out)
{
    int g  = blockIdx.x;
    int n0 = gstart[g], n1 = gstart[g + 1];
    int c    = threadIdx.x & 31;
    int slot = threadIdx.x >> 5;   // 0..7
    float s = 0.f;
    for (int n = n0 + slot; n < n1; n += 8)
        s += h2[n * HID + c];
    __shared__ float red[8][HID];
    red[slot][c] = s;
    __syncthreads();
    if (slot == 0) {
        float tot = 0.f;
#pragma unroll
        for (int i = 0; i < 8; ++i) tot += red[i][c];
        float cntf = fmaxf((float)(n1 - n0), 1.f);
        float p = tot / cntf;
        float sc = p * wc[c];
        float sp = p * wp[c];
        sc += __shfl_xor(sc, 1);  sp += __shfl_xor(sp, 1);
        sc += __shfl_xor(sc, 2);  sp += __shfl_xor(sp, 2);
        sc += __shfl_xor(sc, 4);  sp += __shfl_xor(sp, 4);
        sc += __shfl_xor(sc, 8);  sp += __shfl_xor(sp, 8);
        sc += __shfl_xor(sc, 16); sp += __shfl_xor(sp, 16);
        if (c == 0) {
            out[g]          = sc + bc[0];
            out[NGRAPH + g] = sp + bp[0];
        }
    }
}

extern "C" void kernel_launch(void* const* d_in, const int* in_sizes, int n_in,
                              void* d_out, int out_size, void* d_ws, size_t ws_size,
                              hipStream_t stream)
{
    const float* x     = (const float*)d_in[0];
    const int*   ei    = (const int*)d_in[1];
    const int*   batch = (const int*)d_in[2];
    const float* w1l   = (const float*)d_in[3];
    const float* b1l   = (const float*)d_in[4];
    const float* w1r   = (const float*)d_in[5];
    const float* b1r   = (const float*)d_in[6];
    const float* att1  = (const float*)d_in[7];
    const float* bias1 = (const float*)d_in[8];
    const float* w2l   = (const float*)d_in[9];
    const float* b2l   = (const float*)d_in[10];
    const float* w2r   = (const float*)d_in[11];
    const float* b2r   = (const float*)d_in[12];
    const float* att2  = (const float*)d_in[13];
    const float* bias2 = (const float*)d_in[14];
    const float* wc    = (const float*)d_in[15];
    const float* bc    = (const float*)d_in[16];
    const float* wp    = (const float*)d_in[17];
    const float* bp    = (const float*)d_in[18];
    float* out = (float*)d_out;

    float* ws   = (float*)d_ws;
    // conv1 phase: xlb (bf16 gathered table) in [0 .. 3.2M floats-worth); xr1 at +6.4M
    unsigned short* xlb = (unsigned short*)ws;          // 6,400,000 ushorts = 12.8 MB
    float* xr1  = ws + 6400000;       // 6,400,000 floats
    float* hbuf = ws + 6400000;       // ALIASES xr1 (safe: per-wave read-own-row-then-write)
    // conv2 phase (xlb region dead after k_gat1_fused)
    unsigned short* xlb2 = (unsigned short*)ws;         // 1,600,000 ushorts = 3.2 MB
    float* xr2  = ws + 1600000;       // 1,600,000 floats
    float* h2   = ws + 3200000;       // 1,600,000 floats
    // int region (after 12.8M floats)
    int* ibase   = (int*)(ws + 12800000);
    int* deg     = ibase;              //  50,000
    int* rs      = ibase + 50000;      //  50,001
    int* cur     = ibase + 100001;     //  50,000
    int* csr_src = ibase + 150001;     // 800,000
    int* gstart  = ibase + 950001;     //      65
    int* btot    = ibase + 950101;     //      49
    int* boff    = ibase + 950151;     //      49
    // re-laid-out weights: conv1 bf16 hi/lo frag-order, conv2 fp32
    unsigned short* bh1 = (unsigned short*)(ws + 13800000);   // 32768 ushort
    unsigned short* bl1_ = (unsigned short*)(ws + 13816384);  // 32768 ushort
    float* wtg2 = ws + 13840000;       //  8,192 floats

    // ---- one-time weight re-layout + CSR build + graph boundaries ----
    k_wtrans1<<<128, 256, 0, stream>>>(w1l, w1r, bh1, bl1_);
    k_wtrans2<<<32, 256, 0, stream>>>(w2l, w2r, wtg2);
    hipMemsetAsync(deg, 0, N_NODES * sizeof(int), stream);
    hipMemsetAsync(cur, 0, N_NODES * sizeof(int), stream);
    k_hist<<<(N_EDGES + 255) / 256, 256, 0, stream>>>(ei, deg);
    k_scan_local<<<SCAN_NB, 1024, 0, stream>>>(deg, rs, btot);
    k_scan_btot<<<1, 64, 0, stream>>>(btot, boff);
    k_scan_add<<<SCAN_NB, 1024, 0, stream>>>(rs, boff);
    k_scatter<<<(N_EDGES + 255) / 256, 256, 0, stream>>>(ei, rs, cur, csr_src);
    k_gbound<<<(N_NODES + 1 + 255) / 256, 256, 0, stream>>>(batch, gstart);

    // ---- conv1 ----
    k_transform1<<<(N_NODES + 63) / 64, 256, 0, stream>>>(x, bh1, bl1_, b1l, b1r, xlb, xr1);
    k_gat1_fused<<<(N_NODES * 64 + 255) / 256, 256, 0, stream>>>(rs, csr_src, xlb, xr1, att1, bias1, hbuf);

    // ---- conv2 ----
    k_transform2<<<(N_NODES + 63) / 64, 256, 0, stream>>>(hbuf, wtg2, b2l, b2r, xlb2, xr2);
    k_gat2_fused<<<(N_NODES * 32 + 255) / 256, 256, 0, stream>>>(rs, csr_src, xlb2, xr2, att2, bias2, h2);

    // ---- pool + heads ----
    k_pool_heads<<<NGRAPH, 256, 0, stream>>>(h2, gstart, wc, bc, wp, bp, out);
}